// Round 12
// baseline (535.033 us; speedup 1.0000x reference)
//
#include <hip/hip_runtime.h>
#include <stdint.h>
#include <math.h>

typedef unsigned short u16;
typedef __attribute__((ext_vector_type(8))) short short8;
typedef __attribute__((ext_vector_type(4))) float f32x4;

#define A0C 0.44721359549995793f
#define A1C 0.77459666924148340f
#define INV3C 0.57735026918962584f
#define INV6C 0.40824829046386302f

__device__ __forceinline__ float bf2f(u16 u) {
    unsigned v = ((unsigned)u) << 16; float f; __builtin_memcpy(&f, &v, 4); return f;
}
__device__ __forceinline__ u16 f2bf(float f) {
    unsigned u; __builtin_memcpy(&u, &f, 4);
    u += 0x7fffu + ((u >> 16) & 1u);
    return (u16)(u >> 16);
}

__device__ __forceinline__ void gload_lds16(const void* g, void* l) {
    __builtin_amdgcn_global_load_lds((const __attribute__((address_space(1))) unsigned*)g,
                                     (__attribute__((address_space(3))) unsigned*)l, 16, 0, 0);
}

union S8 { short8 v; u16 h[8]; };

// ---------------- weight transpose + bf16 convert ----------------
struct WDesc { const float* s; u16* d; int n; float sc; };
struct WArgs { WDesc w[12]; };

__global__ void cvt_weights(WArgs args) {
    WDesc wd = args.w[blockIdx.z];
    int n = wd.n;
    int x0 = blockIdx.x * 32, y0 = blockIdx.y * 32;
    if (x0 >= n || y0 >= n) return;
    __shared__ float tile[32][33];
    int tx = threadIdx.x, ty = threadIdx.y;
#pragma unroll
    for (int j = 0; j < 4; j++)
        tile[ty + 8 * j][tx] = wd.s[(size_t)(y0 + ty + 8 * j) * n + x0 + tx];
    __syncthreads();
#pragma unroll
    for (int j = 0; j < 4; j++)
        wd.d[(size_t)(x0 + ty + 8 * j) * n + y0 + tx] = f2bf(tile[tx][ty + 8 * j] * wd.sc);
}

// ---------------- bias pack ----------------
struct BDesc { const float* s; float* d; int n; };
struct BArgs { BDesc b[9]; };
__global__ void pack_bias(BArgs a) {
    BDesc b = a.b[blockIdx.x];
    for (int i = threadIdx.x; i < b.n; i += 256) b.d[i] = b.s[i];
}

// ---------------- prep: f0 = [s,|v|] bf16, XV planar bf16 (8 elems/thread) ----------------
__global__ void prep_f0(const float* __restrict__ x, u16* __restrict__ f0,
                        u16* __restrict__ xv, long ps) {
    int t = blockIdx.x * 256 + threadIdx.x;
    long n = t >> 5;
    int u0 = (t & 31) * 8;
    const float* xr = x + (size_t)n * 1024;
    float4 s0 = *(const float4*)(xr + u0);
    float4 s1 = *(const float4*)(xr + u0 + 4);
    float vv[24];
#pragma unroll
    for (int i = 0; i < 6; i++) {
        float4 w = *(const float4*)(xr + 256 + 3 * u0 + 4 * i);
        vv[4 * i] = w.x; vv[4 * i + 1] = w.y; vv[4 * i + 2] = w.z; vv[4 * i + 3] = w.w;
    }
    float sc[8] = { s0.x, s0.y, s0.z, s0.w, s1.x, s1.y, s1.z, s1.w };
    S8 fs, fn, px, py, pz;
#pragma unroll
    for (int j = 0; j < 8; j++) {
        float a = vv[3 * j], b = vv[3 * j + 1], c = vv[3 * j + 2];
        float nv = sqrtf(a * a + b * b + c * c + 1e-12f);
        fs.h[j] = f2bf(sc[j]);
        fn.h[j] = f2bf(nv);
        px.h[j] = f2bf(a); py.h[j] = f2bf(b); pz.h[j] = f2bf(c);
    }
    size_t o = (size_t)n * 256 + u0;
    *(short8*)(f0 + (size_t)n * 512 + u0) = fs.v;
    *(short8*)(f0 + (size_t)n * 512 + 256 + u0) = fn.v;
    *(short8*)(xv + o) = px.v;
    *(short8*)(xv + ps + o) = py.v;
    *(short8*)(xv + 2 * ps + o) = pz.v;
}

// ---------------- fused 2-layer MLP: G = (silu(F0 @ W1^T + b1)) @ W2^T + b2 ----------------
// Block = 64 rows x side z (512 cols). Phase 1 computes H-strip [64x512] into
// swizzled LDS (never hits HBM). Phase 2: G-strip = Hs @ W2^T + b2.
// Each phase runs 2 n-halves of 256 cols; B tiles [256 cols][64 k] dbuf-staged.
// MFMA operands SWAPPED (mfma(b,a)): lane&15 -> M-row, hk*4+reg -> N-col.
// LDS: Hs 64KB + 2 x (B 32KB + A 8KB) = 144KB -> 1 block/CU.
__global__ __launch_bounds__(512, 2)
void mlp_fused(const u16* __restrict__ F0, int ldf,
               const u16* __restrict__ W1, long w1zs,
               const u16* __restrict__ W2, long w2zs,
               const float* __restrict__ B1, int b1zs,
               const float* __restrict__ B2, int b2zs,
               u16* __restrict__ G, int ldg, int gzoff,
               long nc)
{
    extern __shared__ __align__(16) u16 sm[];
    u16* Hs = sm;                 // [64][512] swizzled : 32768 u16
    u16* St = sm + 32768;         // 2 bufs x (B 16384 | A 4096) u16

    const int tid = threadIdx.x;
    const int lane = tid & 63;
    const int wid = tid >> 6;
    const int lr = lane & 15, hk = lane >> 4;

    int nwg = gridDim.x;
    int lid = blockIdx.x;
    int wg;
    if ((nwg & 7) == 0) { int q = nwg >> 3; wg = (lid & 7) * q + (lid >> 3); }
    else wg = lid;
    const long rows0 = (long)wg * 64;
    const int z = blockIdx.y;

    const u16* W1z = W1 + (size_t)z * w1zs;
    const u16* W2z = W2 + (size_t)z * w2zs;
    const float* b1 = B1 + (size_t)z * b1zs;
    const float* b2 = B2 + (size_t)z * b2zs;

    f32x4 acc[4][2];

    auto stageB = [&](const u16* Bh, int buf, int kt) {
        u16* Bd = St + buf * 20480;
#pragma unroll
        for (int it = 0; it < 4; ++it) {
            int idx = it * 512 + tid;
            int r = idx >> 3, s = idx & 7;
            gload_lds16(Bh + (size_t)r * 512 + kt + ((s ^ (r & 7)) * 8),
                        Bd + (size_t)(it * 512 + (tid & 0x1C0)) * 8);
        }
    };
    auto stageA = [&](int buf, int kt) {
        u16* Ad = St + buf * 20480 + 16384;
        int r = tid >> 3, s = tid & 7;
        gload_lds16(F0 + (rows0 + r) * (size_t)ldf + kt + ((s ^ (r & 7)) * 8),
                    Ad + (size_t)(tid & 0x1C0) * 8);
    };

    auto comp1 = [&](int buf) {
        const u16* Bd = St + buf * 20480;
        const u16* Ad = Bd + 16384;
#pragma unroll
        for (int kk = 0; kk < 2; ++kk) {
            short8 b[2];
#pragma unroll
            for (int n = 0; n < 2; n++) {
                int cb = wid * 32 + n * 16 + lr;
                int sl = (kk * 4 + hk) ^ (cb & 7);
                b[n] = *(const short8*)&Bd[(size_t)cb * 64 + sl * 8];
            }
#pragma unroll
            for (int m = 0; m < 4; m++) {
                int ra = m * 16 + lr;
                int sl = (kk * 4 + hk) ^ (ra & 7);
                short8 a = *(const short8*)&Ad[(size_t)ra * 64 + sl * 8];
#pragma unroll
                for (int n = 0; n < 2; n++)
                    acc[m][n] = __builtin_amdgcn_mfma_f32_16x16x32_bf16(b[n], a, acc[m][n], 0, 0, 0);
            }
        }
    };
    auto comp2 = [&](int buf, int kt) {
        const u16* Bd = St + buf * 20480;
#pragma unroll
        for (int kk = 0; kk < 2; ++kk) {
            short8 b[2];
#pragma unroll
            for (int n = 0; n < 2; n++) {
                int cb = wid * 32 + n * 16 + lr;
                int sl = (kk * 4 + hk) ^ (cb & 7);
                b[n] = *(const short8*)&Bd[(size_t)cb * 64 + sl * 8];
            }
#pragma unroll
            for (int m = 0; m < 4; m++) {
                int ra = m * 16 + lr;
                int slot = ((kt >> 3) + kk * 4 + hk) ^ (ra & 7);
                short8 a = *(const short8*)&Hs[(size_t)ra * 512 + slot * 8];
#pragma unroll
                for (int n = 0; n < 2; n++)
                    acc[m][n] = __builtin_amdgcn_mfma_f32_16x16x32_bf16(b[n], a, acc[m][n], 0, 0, 0);
            }
        }
    };

    // ---- Phase 1: H-strip into LDS ----
    for (int nh = 0; nh < 2; ++nh) {
        const u16* Bh = W1z + (size_t)nh * 256 * 512;
#pragma unroll
        for (int m = 0; m < 4; m++)
#pragma unroll
            for (int n = 0; n < 2; n++) acc[m][n] = (f32x4){0.f, 0.f, 0.f, 0.f};
        stageB(Bh, 0, 0);
        stageA(0, 0);
        __syncthreads();
        int buf = 0;
        for (int t = 0; t < 8; ++t) {
            if (t + 1 < 8) { stageB(Bh, buf ^ 1, (t + 1) << 6); stageA(buf ^ 1, (t + 1) << 6); }
            comp1(buf);
            __syncthreads();
            buf ^= 1;
        }
        // bias1 + silu -> Hs (swizzled)
#pragma unroll
        for (int m = 0; m < 4; m++) {
            int row = m * 16 + lr;
#pragma unroll
            for (int n = 0; n < 2; n++) {
                int col = nh * 256 + wid * 32 + n * 16 + hk * 4;
                float4 bb = *(const float4*)&b1[col];
                float v0 = acc[m][n][0] + bb.x;
                float v1 = acc[m][n][1] + bb.y;
                float v2 = acc[m][n][2] + bb.z;
                float v3 = acc[m][n][3] + bb.w;
                v0 = v0 * (1.0f / (1.0f + __expf(-v0)));
                v1 = v1 * (1.0f / (1.0f + __expf(-v1)));
                v2 = v2 * (1.0f / (1.0f + __expf(-v2)));
                v3 = v3 * (1.0f / (1.0f + __expf(-v3)));
                uint2 st;
                st.x = (unsigned)f2bf(v0) | ((unsigned)f2bf(v1) << 16);
                st.y = (unsigned)f2bf(v2) | ((unsigned)f2bf(v3) << 16);
                int slot = (col >> 3) ^ (row & 7);
                *(uint2*)&Hs[(size_t)row * 512 + slot * 8 + (col & 7)] = st;
            }
        }
        __syncthreads();
    }

    // ---- Phase 2: G-strip = Hs @ W2^T + b2 ----
    for (int nh = 0; nh < 2; ++nh) {
        const u16* Bh = W2z + (size_t)nh * 256 * 512;
#pragma unroll
        for (int m = 0; m < 4; m++)
#pragma unroll
            for (int n = 0; n < 2; n++) acc[m][n] = (f32x4){0.f, 0.f, 0.f, 0.f};
        stageB(Bh, 0, 0);
        __syncthreads();
        int buf = 0;
        for (int t = 0; t < 8; ++t) {
            if (t + 1 < 8) stageB(Bh, buf ^ 1, (t + 1) << 6);
            comp2(buf, t << 6);
            __syncthreads();
            buf ^= 1;
        }
        // bias2 -> G (packed 8B stores)
#pragma unroll
        for (int m = 0; m < 4; m++) {
            int row = m * 16 + lr;
            u16* grow = G + (rows0 + row) * (size_t)ldg + (size_t)z * gzoff;
#pragma unroll
            for (int n = 0; n < 2; n++) {
                int col = nh * 256 + wid * 32 + n * 16 + hk * 4;
                float4 bb = *(const float4*)&b2[col];
                float v0 = acc[m][n][0] + bb.x;
                float v1 = acc[m][n][1] + bb.y;
                float v2 = acc[m][n][2] + bb.z;
                float v3 = acc[m][n][3] + bb.w;
                uint2 st;
                st.x = (unsigned)f2bf(v0) | ((unsigned)f2bf(v1) << 16);
                st.y = (unsigned)f2bf(v2) | ((unsigned)f2bf(v3) << 16);
                *(uint2*)(grow + col) = st;
            }
        }
    }
}

// ---------------- GEMM 256x256 tile, BK=64, dbuf LDS, T2 swizzle ----------------
// a_direct path (mode 0 / p==0): T4 counted-vmcnt pipeline.
// mode 2 p>0 (gated, ds_write staging): plain dbuf loop.
// MFMA operands SWAPPED (mfma(b,a)): lane&15 -> M-row, hk*4+reg -> N-col.
__global__ __launch_bounds__(512, 2)
void gemm256(const u16* __restrict__ Ap, int lda, long az,
             const u16* __restrict__ xsrc,
             const u16* __restrict__ gp, int gld, long gz,
             const u16* __restrict__ Bt, long bz, long bw,
             const float* __restrict__ bias, int bsz,
             u16* __restrict__ C, int ldc, long czs, long czp,
             int K, long nc, int mode, int act, int nshift)
{
    extern __shared__ __align__(16) u16 sm[];
    u16* As = sm;
    u16* Bs = sm + 32768;

    const int tid = threadIdx.x;
    const int lane = tid & 63;
    const int wid = tid >> 6;
    const int wr = wid >> 2, wc = wid & 3;
    const int lr = lane & 15, hk = lane >> 4;

    int nwg = gridDim.x;
    int lid = blockIdx.x;
    int wg;
    if ((nwg & 7) == 0) { int q = nwg >> 3; wg = (lid & 7) * q + (lid >> 3); }
    else wg = lid;
    const long row0 = (long)(wg >> nshift) * 256;
    const int n0 = (wg & ((1 << nshift) - 1)) * 256;
    const int zi = blockIdx.y;

    long p = 0, rr0 = row0;
    if (mode == 2) { p = row0 / nc; rr0 = row0 - p * nc; }

    const u16* Bz = Bt + (size_t)zi * bz + ((mode == 2 && p > 0) ? bw : 0);
    const long cbase = (mode == 2) ? (zi * czs + p * czp + rr0 * ldc)
                                   : (zi * czs + row0 * ldc);

    f32x4 acc[8][4];
#pragma unroll
    for (int m = 0; m < 8; m++)
#pragma unroll
        for (int n = 0; n < 4; n++) acc[m][n] = (f32x4){0.f, 0.f, 0.f, 0.f};

    auto stageB = [&](int buf, int kt) {
#pragma unroll
        for (int it = 0; it < 4; ++it) {
            int idx = it * 512 + tid;
            int r = idx >> 3, s = idx & 7;
            const u16* g = Bz + (size_t)(n0 + r) * K + kt + ((s ^ (r & 7)) * 8);
            u16* l = Bs + buf * 16384 + (size_t)(it * 512 + (tid & 0x1C0)) * 8;
            gload_lds16(g, l);
        }
    };
    auto stageA0 = [&](int buf, int kt) {
#pragma unroll
        for (int it = 0; it < 4; ++it) {
            int idx = it * 512 + tid;
            int r = idx >> 3, s = idx & 7;
            const u16* g = Ap + (size_t)zi * az + (rr0 + r) * (size_t)lda + kt + ((s ^ (r & 7)) * 8);
            u16* l = As + buf * 16384 + (size_t)(it * 512 + (tid & 0x1C0)) * 8;
            gload_lds16(g, l);
        }
    };
    auto stageA2 = [&](int buf, int kt) {
#pragma unroll
        for (int it = 0; it < 4; ++it) {
            int idx = it * 512 + tid;
            int r = idx >> 3, s = idx & 7;
            int u = kt + s * 8;
            S8 gg, tu, pk;
            gg.v = *(const short8*)(gp + (size_t)zi * gz + (rr0 + r) * (size_t)gld + 256 + u);
            tu.v = *(const short8*)(xsrc + (size_t)(row0 - nc + r) * 256 + u);
#pragma unroll
            for (int j = 0; j < 8; j++) pk.h[j] = f2bf(bf2f(tu.h[j]) * bf2f(gg.h[j]));
            *(short8*)&As[buf * 16384 + ((size_t)r * 8 + (s ^ (r & 7))) * 8] = pk.v;
        }
    };

    auto compute = [&](int buf) {
        const int ao = buf * 16384, bo = buf * 16384;
#pragma unroll
        for (int kk = 0; kk < 2; ++kk) {
            short8 b[4];
#pragma unroll
            for (int n = 0; n < 4; n++) {
                int cb = wc * 64 + n * 16 + lr;
                int sl = (kk * 4 + hk) ^ (cb & 7);
                b[n] = *(const short8*)&Bs[bo + (size_t)cb * 64 + sl * 8];
            }
#pragma unroll
            for (int m = 0; m < 8; m++) {
                int ra = wr * 128 + m * 16 + lr;
                int sl = (kk * 4 + hk) ^ (ra & 7);
                short8 a = *(const short8*)&As[ao + (size_t)ra * 64 + sl * 8];
#pragma unroll
                for (int n = 0; n < 4; n++)
                    acc[m][n] = __builtin_amdgcn_mfma_f32_16x16x32_bf16(b[n], a, acc[m][n], 0, 0, 0);
            }
        }
    };

    const bool a_direct = (mode == 0) || (p == 0);
    const int nt = K >> 6;
    int buf = 0;

    if (a_direct) {
        stageB(0, 0);
        stageA0(0, 0);
        for (int t = 0; t < nt; ++t) {
            if (t + 1 < nt) {
                int kt = (t + 1) << 6;
                stageB(buf ^ 1, kt);
                stageA0(buf ^ 1, kt);
                asm volatile("s_waitcnt vmcnt(8)" ::: "memory");
            } else {
                asm volatile("s_waitcnt vmcnt(0)" ::: "memory");
            }
            __builtin_amdgcn_s_barrier();
            __builtin_amdgcn_sched_barrier(0);
            compute(buf);
            __builtin_amdgcn_s_barrier();
            buf ^= 1;
        }
    } else {
        stageB(0, 0);
        stageA2(0, 0);
        __syncthreads();
        for (int t = 0; t < nt; ++t) {
            if (t + 1 < nt) {
                int kt = (t + 1) << 6;
                stageB(buf ^ 1, kt);
                stageA2(buf ^ 1, kt);
            }
            compute(buf);
            __syncthreads();
            buf ^= 1;
        }
    }

    const bool use_bias = bias && (mode == 0 || p == 0);
#pragma unroll
    for (int m = 0; m < 8; m++) {
        long rit = wr * 128 + m * 16 + lr;
        u16* crow = C + cbase + rit * (size_t)ldc;
#pragma unroll
        for (int n = 0; n < 4; n++) {
            int col = n0 + wc * 64 + n * 16 + hk * 4;
            float4 bb = use_bias ? *(const float4*)&bias[(size_t)zi * bsz + col]
                                 : (float4){0.f, 0.f, 0.f, 0.f};
            float v0 = acc[m][n][0] + bb.x;
            float v1 = acc[m][n][1] + bb.y;
            float v2 = acc[m][n][2] + bb.z;
            float v3 = acc[m][n][3] + bb.w;
            if (act) {
                v0 = v0 * (1.0f / (1.0f + __expf(-v0)));
                v1 = v1 * (1.0f / (1.0f + __expf(-v1)));
                v2 = v2 * (1.0f / (1.0f + __expf(-v2)));
                v3 = v3 * (1.0f / (1.0f + __expf(-v3)));
            }
            uint2 st;
            st.x = (unsigned)f2bf(v0) | ((unsigned)f2bf(v1) << 16);
            st.y = (unsigned)f2bf(v2) | ((unsigned)f2bf(v3) << 16);
            *(uint2*)(crow + col) = st;
        }
    }
}

// ---------------- tensor product + residual -> f0', tv planes (8 elems/thread) ----------------
__global__ void tp_res(const u16* __restrict__ xl, const u16* xr_,
                       const float* __restrict__ tpw, const u16* __restrict__ xv,
                       u16* f0, u16* tv, long ps)
{
    int t = blockIdx.x * 256 + threadIdx.x;
    long n = t >> 5;
    int u0 = (t & 31) * 8;
    size_t o = (size_t)n * 256 + u0;

    S8 S1, AX, AY, AZ, S2, BX, BY, BZ, XS, RX, RY, RZ;
    S1.v = *(const short8*)(xl + o);
    AX.v = *(const short8*)(xl + ps + o);
    AY.v = *(const short8*)(xl + 2 * ps + o);
    AZ.v = *(const short8*)(xl + 3 * ps + o);
    S2.v = *(const short8*)(xr_ + o);
    BX.v = *(const short8*)(xr_ + ps + o);
    BY.v = *(const short8*)(xr_ + 2 * ps + o);
    BZ.v = *(const short8*)(xr_ + 3 * ps + o);
    XS.v = *(const short8*)(f0 + (size_t)n * 512 + u0);
    RX.v = *(const short8*)(xv + o);
    RY.v = *(const short8*)(xv + ps + o);
    RZ.v = *(const short8*)(xv + 2 * ps + o);

    float W[5][8];
#pragma unroll
    for (int q = 0; q < 5; q++) {
        float4 a = *(const float4*)(tpw + q * 256 + u0);
        float4 b = *(const float4*)(tpw + q * 256 + u0 + 4);
        W[q][0] = a.x; W[q][1] = a.y; W[q][2] = a.z; W[q][3] = a.w;
        W[q][4] = b.x; W[q][5] = b.y; W[q][6] = b.z; W[q][7] = b.w;
    }

    S8 O0, NV, TX, TY, TZ;
#pragma unroll
    for (int j = 0; j < 8; j++) {
        float s1 = bf2f(S1.h[j]), a1x = bf2f(AX.h[j]), a1y = bf2f(AY.h[j]), a1z = bf2f(AZ.h[j]);
        float s2 = bf2f(S2.h[j]), b1x = bf2f(BX.h[j]), b1y = bf2f(BY.h[j]), b1z = bf2f(BZ.h[j]);
        float dot = a1x * b1x + a1y * b1y + a1z * b1z;
        float cx = a1y * b1z - a1z * b1y;
        float cy = a1z * b1x - a1x * b1z;
        float cz = a1x * b1y - a1y * b1x;
        float out0 = A0C * (W[0][j] * s1 * s2 + W[3][j] * INV3C * dot) + bf2f(XS.h[j]);
        float ox = A1C * (INV3C * (W[1][j] * s1 * b1x + W[2][j] * s2 * a1x) + INV6C * W[4][j] * cx) + bf2f(RX.h[j]);
        float oy = A1C * (INV3C * (W[1][j] * s1 * b1y + W[2][j] * s2 * a1y) + INV6C * W[4][j] * cy) + bf2f(RY.h[j]);
        float oz = A1C * (INV3C * (W[1][j] * s1 * b1z + W[2][j] * s2 * a1z) + INV6C * W[4][j] * cz) + bf2f(RZ.h[j]);
        float nv = sqrtf(ox * ox + oy * oy + oz * oz + 1e-12f);
        O0.h[j] = f2bf(out0);
        NV.h[j] = f2bf(nv);
        TX.h[j] = f2bf(ox); TY.h[j] = f2bf(oy); TZ.h[j] = f2bf(oz);
    }
    *(short8*)(f0 + (size_t)n * 512 + u0) = O0.v;
    *(short8*)(f0 + (size_t)n * 512 + 256 + u0) = NV.v;
    *(short8*)(tv + o) = TX.v;
    *(short8*)(tv + ps + o) = TY.v;
    *(short8*)(tv + 2 * ps + o) = TZ.v;
}

// ---------------- repack planar -> interleaved + old_fii (8 elems/thread) ----------------
__global__ void repack(const u16* __restrict__ outp, const float* __restrict__ old,
                       float* __restrict__ out, long ps)
{
    int t = blockIdx.x * 256 + threadIdx.x;
    long n = t >> 5;
    int u0 = (t & 31) * 8;
    size_t o = (size_t)n * 256 + u0;

    S8 S, VX, VY, VZ;
    S.v  = *(const short8*)(outp + o);
    VX.v = *(const short8*)(outp + ps + o);
    VY.v = *(const short8*)(outp + 2 * ps + o);
    VZ.v = *(const short8*)(outp + 3 * ps + o);

    const float* oldr = old + (size_t)n * 1024;
    float* outr = out + (size_t)n * 1024;

#pragma unroll
    for (int i = 0; i < 2; i++) {
        float4 ov = *(const float4*)(oldr + u0 + 4 * i);
        float4 r;
        r.x = ov.x + bf2f(S.h[4 * i]);
        r.y = ov.y + bf2f(S.h[4 * i + 1]);
        r.z = ov.z + bf2f(S.h[4 * i + 2]);
        r.w = ov.w + bf2f(S.h[4 * i + 3]);
        *(float4*)(outr + u0 + 4 * i) = r;
    }
    float vv[24];
#pragma unroll
    for (int j = 0; j < 8; j++) {
        vv[3 * j] = bf2f(VX.h[j]);
        vv[3 * j + 1] = bf2f(VY.h[j]);
        vv[3 * j + 2] = bf2f(VZ.h[j]);
    }
#pragma unroll
    for (int i = 0; i < 6; i++) {
        float4 ov = *(const float4*)(oldr + 256 + 3 * u0 + 4 * i);
        float4 r;
        r.x = ov.x + vv[4 * i];
        r.y = ov.y + vv[4 * i + 1];
        r.z = ov.z + vv[4 * i + 2];
        r.w = ov.w + vv[4 * i + 3];
        *(float4*)(outr + 256 + 3 * u0 + 4 * i) = r;
    }
}

// weight offsets (u16 elements)
enum {
    OFF_ng12w1 = 0,        // 2 x 512x512 (z stride 262144)
    OFF_ng1w2  = 524288,   // 2 x 512x512 (stride 262144)
    OFF_ngow1  = 1048576,
    OFF_ngow2  = 1310720,
    OFF_l12w0  = 1572864,  // 2 x 256x256 (stride 65536)
    OFF_l12w1  = 1703936,  // 2 x 256x256
    OFF_l3w0   = 1835008,
    OFF_l3w1   = 1900544
};
#define BIAS_BYTE_OFF 3932160
enum { BOFF_mlp1 = 0, BOFF_mlp2 = 1024, BOFF_ngo1 = 2048, BOFF_ngo2 = 2560,
       BOFF_l12 = 3072, BOFF_l3 = 3584 };

extern "C" void kernel_launch(void* const* d_in, const int* in_sizes, int n_in,
                              void* d_out, int out_size, void* d_ws, size_t ws_size,
                              hipStream_t stream) {
    const float* x      = (const float*)d_in[0];
    const float* oldf   = (const float*)d_in[1];
    const float* ng1_w1 = (const float*)d_in[2];
    const float* ng1_b1 = (const float*)d_in[3];
    const float* ng1_w2 = (const float*)d_in[4];
    const float* ng1_b2 = (const float*)d_in[5];
    const float* ng2_w1 = (const float*)d_in[6];
    const float* ng2_b1 = (const float*)d_in[7];
    const float* ng2_w2 = (const float*)d_in[8];
    const float* ng2_b2 = (const float*)d_in[9];
    const float* ngo_w1 = (const float*)d_in[10];
    const float* ngo_b1 = (const float*)d_in[11];
    const float* ngo_w2 = (const float*)d_in[12];
    const float* ngo_b2 = (const float*)d_in[13];
    const float* l1_w0  = (const float*)d_in[14];
    const float* l1_b0  = (const float*)d_in[15];
    const float* l1_w1  = (const float*)d_in[16];
    const float* l2_w0  = (const float*)d_in[17];
    const float* l2_b0  = (const float*)d_in[18];
    const float* l2_w1  = (const float*)d_in[19];
    const float* l3_w0  = (const float*)d_in[20];
    const float* l3_b0  = (const float*)d_in[21];
    const float* l3_w1  = (const float*)d_in[22];
    const float* tpw    = (const float*)d_in[23];

    u16* wts = (u16*)d_ws;
    char* wsb = (char*)d_ws;
    float* biasf = (float*)(wsb + BIAS_BYTE_OFF);

    WArgs wa;
    wa.w[0]  = { ng1_w1, wts + OFF_ng12w1,          512, 1.0f };
    wa.w[1]  = { ng2_w1, wts + OFF_ng12w1 + 262144, 512, 1.0f };
    wa.w[2]  = { ng1_w2, wts + OFF_ng1w2,           512, 1.0f };
    wa.w[3]  = { ng2_w2, wts + OFF_ng1w2 + 262144,  512, 1.0f };
    wa.w[4]  = { ngo_w1, wts + OFF_ngow1,           512, 1.0f };
    wa.w[5]  = { ngo_w2, wts + OFF_ngow2,           512, 1.0f };
    wa.w[6]  = { l1_w0, wts + OFF_l12w0,            256, 0.0625f };
    wa.w[7]  = { l2_w0, wts + OFF_l12w0 + 65536,    256, 0.0625f };
    wa.w[8]  = { l1_w1, wts + OFF_l12w1,            256, 0.0625f };
    wa.w[9]  = { l2_w1, wts + OFF_l12w1 + 65536,    256, 0.0625f };
    wa.w[10] = { l3_w0, wts + OFF_l3w0,             256, 0.0625f };
    wa.w[11] = { l3_w1, wts + OFF_l3w1,             256, 0.0625f };
    cvt_weights<<<dim3(16, 16, 12), dim3(32, 8), 0, stream>>>(wa);

    BArgs ba;
    ba.b[0] = { ng1_b1, biasf + BOFF_mlp1,       512 };
    ba.b[1] = { ng2_b1, biasf + BOFF_mlp1 + 512, 512 };
    ba.b[2] = { ng1_b2, biasf + BOFF_mlp2,       512 };
    ba.b[3] = { ng2_b2, biasf + BOFF_mlp2 + 512, 512 };
    ba.b[4] = { ngo_b1, biasf + BOFF_ngo1,       512 };
    ba.b[5] = { ngo_b2, biasf + BOFF_ngo2,       512 };
    ba.b[6] = { l1_b0, biasf + BOFF_l12,         256 };
    ba.b[7] = { l2_b0, biasf + BOFF_l12 + 256,   256 };
    ba.b[8] = { l3_b0, biasf + BOFF_l3,          256 };
    pack_bias<<<9, 256, 0, stream>>>(ba);

    long Nn = (long)in_sizes[0] / 1024;

    // chunking: ws fit only (peak = 4MiB + Nc*10752 bytes)
    int c = 1;
    while (c < 256 &&
           (unsigned long long)(4ULL << 20) + (unsigned long long)(Nn / c) * 10752ULL > (unsigned long long)ws_size)
        c <<= 1;
    long Nc = Nn / c;

    u16* F0 = (u16*)(wsb + (4 << 20));       // [Nc,512]
    u16* H  = F0 + (size_t)Nc * 512;         // [Nc,1024] (unused now, layout kept)
    u16* G  = H + (size_t)Nc * 1024;         // [Nc,1024]
    u16* XV = G + (size_t)Nc * 1024;         // [3][Nc,256]
    u16* XL = XV + (size_t)Nc * 768;         // [2 sides][4 planes][Nc,256]
    long ps = Nc * 256;
    u16* XR = XL + 4 * ps;
    u16* TV = XR + ps;                       // aliases XR vector planes
    u16* OUTP = XL;                          // aliases XL (dead after tp_res)

    dim3 blk(512);
    const size_t SMEM = 131072;
    const size_t SMEM_MLP = 147456;          // Hs 64KB + 2x(B 32KB + A 8KB)
    int mt = (int)(Nc / 256);
    int fb = (int)(Nc / 64);
    int eb = (int)(Nc / 8);

    for (int ch = 0; ch < c; ++ch) {
        const float* xk  = x + (size_t)ch * Nc * 1024;
        const float* ok  = oldf + (size_t)ch * Nc * 1024;
        float* outk = (float*)d_out + (size_t)ch * Nc * 1024;

        prep_f0<<<eb, 256, 0, stream>>>(xk, F0, XV, ps);

        // fused ng1|ng2 MLP: G[:, z*512..] = silu(F0@w1_z^T+b1_z)@w2_z^T+b2_z
        mlp_fused<<<dim3(fb, 2), blk, SMEM_MLP, stream>>>(
            F0, 512, wts + OFF_ng12w1, 262144, wts + OFF_ng1w2, 262144,
            biasf + BOFF_mlp1, 512, biasf + BOFF_mlp2, 512, G, 1024, 512, Nc);

        // merged irrep-linears lin1/lin2: z=2 sides, M=4*Nc (plane 0 scalar, 1-3 gated XV)
        gemm256<<<dim3(mt * 4, 2), blk, SMEM, stream>>>(G, 1024, 512, XV, G, 1024, 512,
            wts + OFF_l12w0, 65536, 131072, biasf + BOFF_l12, 256, XL, 256, 4 * ps, ps, 256, Nc, 2, 0, 0);

        // tensor product + residual -> F0', TV
        tp_res<<<eb, 256, 0, stream>>>(XL, XR, tpw, XV, F0, TV, ps);

        // fused ngo MLP: G[Nc,512] = silu(F0'@ngow1^T+b1)@ngow2^T+b2
        mlp_fused<<<dim3(fb, 1), blk, SMEM_MLP, stream>>>(
            F0, 512, wts + OFF_ngow1, 0, wts + OFF_ngow2, 0,
            biasf + BOFF_ngo1, 0, biasf + BOFF_ngo2, 0, G, 512, 0, Nc);

        // merged lin3: z=1, M=4*Nc (plane 0 scalar from G, 1-3 gated TV)
        gemm256<<<dim3(mt * 4, 1), blk, SMEM, stream>>>(G, 512, 0, TV, G, 512, 0,
            wts + OFF_l3w0, 0, 65536, biasf + BOFF_l3, 0, OUTP, 256, 0, ps, 256, Nc, 2, 0, 0);

        // repack + old_fii -> out
        repack<<<eb, 256, 0, stream>>>(OUTP, ok, outk, ps);
    }
}

// Round 13
// 517.471 us; speedup vs baseline: 1.0339x; 1.0339x over previous
//
#include <hip/hip_runtime.h>
#include <stdint.h>
#include <math.h>

typedef unsigned short u16;
typedef __attribute__((ext_vector_type(8))) short short8;
typedef __attribute__((ext_vector_type(4))) float f32x4;

#define A0C 0.44721359549995793f
#define A1C 0.77459666924148340f
#define INV3C 0.57735026918962584f
#define INV6C 0.40824829046386302f

__device__ __forceinline__ float bf2f(u16 u) {
    unsigned v = ((unsigned)u) << 16; float f; __builtin_memcpy(&f, &v, 4); return f;
}
__device__ __forceinline__ u16 f2bf(float f) {
    unsigned u; __builtin_memcpy(&u, &f, 4);
    u += 0x7fffu + ((u >> 16) & 1u);
    return (u16)(u >> 16);
}

__device__ __forceinline__ void gload_lds16(const void* g, void* l) {
    __builtin_amdgcn_global_load_lds((const __attribute__((address_space(1))) unsigned*)g,
                                     (__attribute__((address_space(3))) unsigned*)l, 16, 0, 0);
}

union S8 { short8 v; u16 h[8]; };

// ---------------- weight transpose + bf16 convert ----------------
struct WDesc { const float* s; u16* d; int n; float sc; };
struct WArgs { WDesc w[12]; };

__global__ void cvt_weights(WArgs args) {
    WDesc wd = args.w[blockIdx.z];
    int n = wd.n;
    int x0 = blockIdx.x * 32, y0 = blockIdx.y * 32;
    if (x0 >= n || y0 >= n) return;
    __shared__ float tile[32][33];
    int tx = threadIdx.x, ty = threadIdx.y;
#pragma unroll
    for (int j = 0; j < 4; j++)
        tile[ty + 8 * j][tx] = wd.s[(size_t)(y0 + ty + 8 * j) * n + x0 + tx];
    __syncthreads();
#pragma unroll
    for (int j = 0; j < 4; j++)
        wd.d[(size_t)(x0 + ty + 8 * j) * n + y0 + tx] = f2bf(tile[tx][ty + 8 * j] * wd.sc);
}

// ---------------- bias pack ----------------
struct BDesc { const float* s; float* d; int n; };
struct BArgs { BDesc b[9]; };
__global__ void pack_bias(BArgs a) {
    BDesc b = a.b[blockIdx.x];
    for (int i = threadIdx.x; i < b.n; i += 256) b.d[i] = b.s[i];
}

// ---------------- prep: f0 = [s,|v|] bf16, XV planar bf16 (8 elems/thread) ----------------
__global__ void prep_f0(const float* __restrict__ x, u16* __restrict__ f0,
                        u16* __restrict__ xv, long ps) {
    int t = blockIdx.x * 256 + threadIdx.x;
    long n = t >> 5;
    int u0 = (t & 31) * 8;
    const float* xr = x + (size_t)n * 1024;
    float4 s0 = *(const float4*)(xr + u0);
    float4 s1 = *(const float4*)(xr + u0 + 4);
    float vv[24];
#pragma unroll
    for (int i = 0; i < 6; i++) {
        float4 w = *(const float4*)(xr + 256 + 3 * u0 + 4 * i);
        vv[4 * i] = w.x; vv[4 * i + 1] = w.y; vv[4 * i + 2] = w.z; vv[4 * i + 3] = w.w;
    }
    float sc[8] = { s0.x, s0.y, s0.z, s0.w, s1.x, s1.y, s1.z, s1.w };
    S8 fs, fn, px, py, pz;
#pragma unroll
    for (int j = 0; j < 8; j++) {
        float a = vv[3 * j], b = vv[3 * j + 1], c = vv[3 * j + 2];
        float nv = sqrtf(a * a + b * b + c * c + 1e-12f);
        fs.h[j] = f2bf(sc[j]);
        fn.h[j] = f2bf(nv);
        px.h[j] = f2bf(a); py.h[j] = f2bf(b); pz.h[j] = f2bf(c);
    }
    size_t o = (size_t)n * 256 + u0;
    *(short8*)(f0 + (size_t)n * 512 + u0) = fs.v;
    *(short8*)(f0 + (size_t)n * 512 + 256 + u0) = fn.v;
    *(short8*)(xv + o) = px.v;
    *(short8*)(xv + ps + o) = py.v;
    *(short8*)(xv + 2 * ps + o) = pz.v;
}

// ---------------- GEMM 256x256 tile, BK=64, dbuf LDS, T2 swizzle ----------------
// a_direct path (mode 0 / p==0): T4 counted-vmcnt pipeline.
// mode 2 p>0 (gated): REORDERED staging — A reg-loads issued BEFORE stageB's
// gload_lds, pack AFTER compute. The pack's implicit s_waitcnt then only waits
// the A regs (vmcnt(4)); B loads stay in flight across compute (fixes the
// FIFO-vmcnt full-drain that serialized every K-step).
// If fout!=nullptr and mode2 p==0: epilogue writes f32 out = acc+bias+old
// directly (coalesced float4), skipping the planar C store.
// MFMA operands SWAPPED (mfma(b,a)): lane&15 -> M-row, hk*4+reg -> N-col.
__global__ __launch_bounds__(512, 2)
void gemm256(const u16* __restrict__ Ap, int lda, long az,
             const u16* __restrict__ xsrc,
             const u16* __restrict__ gp, int gld, long gz,
             const u16* __restrict__ Bt, long bz, long bw,
             const float* __restrict__ bias, int bsz,
             u16* __restrict__ C, int ldc, long czs, long czp,
             int K, long nc, int mode, int act, int nshift,
             const float* __restrict__ oldv, float* __restrict__ fout)
{
    extern __shared__ __align__(16) u16 sm[];
    u16* As = sm;
    u16* Bs = sm + 32768;

    const int tid = threadIdx.x;
    const int lane = tid & 63;
    const int wid = tid >> 6;
    const int wr = wid >> 2, wc = wid & 3;
    const int lr = lane & 15, hk = lane >> 4;

    int nwg = gridDim.x;
    int lid = blockIdx.x;
    int wg;
    if ((nwg & 7) == 0) { int q = nwg >> 3; wg = (lid & 7) * q + (lid >> 3); }
    else wg = lid;
    const long row0 = (long)(wg >> nshift) * 256;
    const int n0 = (wg & ((1 << nshift) - 1)) * 256;
    const int zi = blockIdx.y;

    long p = 0, rr0 = row0;
    if (mode == 2) { p = row0 / nc; rr0 = row0 - p * nc; }

    const u16* Bz = Bt + (size_t)zi * bz + ((mode == 2 && p > 0) ? bw : 0);
    const long cbase = (mode == 2) ? (zi * czs + p * czp + rr0 * ldc)
                                   : (zi * czs + row0 * ldc);

    f32x4 acc[8][4];
#pragma unroll
    for (int m = 0; m < 8; m++)
#pragma unroll
        for (int n = 0; n < 4; n++) acc[m][n] = (f32x4){0.f, 0.f, 0.f, 0.f};

    auto stageB = [&](int buf, int kt) {
#pragma unroll
        for (int it = 0; it < 4; ++it) {
            int idx = it * 512 + tid;
            int r = idx >> 3, s = idx & 7;
            const u16* g = Bz + (size_t)(n0 + r) * K + kt + ((s ^ (r & 7)) * 8);
            u16* l = Bs + buf * 16384 + (size_t)(it * 512 + (tid & 0x1C0)) * 8;
            gload_lds16(g, l);
        }
    };
    auto stageA0 = [&](int buf, int kt) {
#pragma unroll
        for (int it = 0; it < 4; ++it) {
            int idx = it * 512 + tid;
            int r = idx >> 3, s = idx & 7;
            const u16* g = Ap + (size_t)zi * az + (rr0 + r) * (size_t)lda + kt + ((s ^ (r & 7)) * 8);
            u16* l = As + buf * 16384 + (size_t)(it * 512 + (tid & 0x1C0)) * 8;
            gload_lds16(g, l);
        }
    };

    // mode-2 A staging split: reg loads (issue-early) / pack+ds_write (late)
    S8 rg[4], rt[4];
    auto loadA2 = [&](int kt) {
#pragma unroll
        for (int it = 0; it < 4; ++it) {
            int idx = it * 512 + tid;
            int r = idx >> 3, s = idx & 7;
            int u = kt + s * 8;
            rg[it].v = *(const short8*)(gp + (size_t)zi * gz + (rr0 + r) * (size_t)gld + 256 + u);
            rt[it].v = *(const short8*)(xsrc + (size_t)(row0 - nc + r) * 256 + u);
        }
    };
    auto packA2 = [&](int buf) {
#pragma unroll
        for (int it = 0; it < 4; ++it) {
            int idx = it * 512 + tid;
            int r = idx >> 3, s = idx & 7;
            S8 pk;
#pragma unroll
            for (int j = 0; j < 8; j++) pk.h[j] = f2bf(bf2f(rt[it].h[j]) * bf2f(rg[it].h[j]));
            *(short8*)&As[buf * 16384 + ((size_t)r * 8 + (s ^ (r & 7))) * 8] = pk.v;
        }
    };

    auto compute = [&](int buf) {
        const int ao = buf * 16384, bo = buf * 16384;
#pragma unroll
        for (int kk = 0; kk < 2; ++kk) {
            short8 b[4];
#pragma unroll
            for (int n = 0; n < 4; n++) {
                int cb = wc * 64 + n * 16 + lr;
                int sl = (kk * 4 + hk) ^ (cb & 7);
                b[n] = *(const short8*)&Bs[bo + (size_t)cb * 64 + sl * 8];
            }
#pragma unroll
            for (int m = 0; m < 8; m++) {
                int ra = wr * 128 + m * 16 + lr;
                int sl = (kk * 4 + hk) ^ (ra & 7);
                short8 a = *(const short8*)&As[ao + (size_t)ra * 64 + sl * 8];
#pragma unroll
                for (int n = 0; n < 4; n++)
                    acc[m][n] = __builtin_amdgcn_mfma_f32_16x16x32_bf16(b[n], a, acc[m][n], 0, 0, 0);
            }
        }
    };

    const bool a_direct = (mode == 0) || (p == 0);
    const int nt = K >> 6;
    int buf = 0;

    if (a_direct) {
        stageB(0, 0);
        stageA0(0, 0);
        for (int t = 0; t < nt; ++t) {
            if (t + 1 < nt) {
                int kt = (t + 1) << 6;
                stageB(buf ^ 1, kt);
                stageA0(buf ^ 1, kt);
                asm volatile("s_waitcnt vmcnt(8)" ::: "memory");
            } else {
                asm volatile("s_waitcnt vmcnt(0)" ::: "memory");
            }
            __builtin_amdgcn_s_barrier();
            __builtin_amdgcn_sched_barrier(0);
            compute(buf);
            __builtin_amdgcn_s_barrier();
            buf ^= 1;
        }
    } else {
        // prologue: A regs first, then B async, pack (waits regs only), barrier
        loadA2(0);
        stageB(0, 0);
        packA2(0);
        __syncthreads();
        for (int t = 0; t < nt; ++t) {
            const bool more = (t + 1 < nt);
            if (more) {
                int kt = (t + 1) << 6;
                loadA2(kt);          // issue A regs FIRST (oldest in vmcnt FIFO)
                stageB(buf ^ 1, kt); // B gload_lds younger -> stays in flight
            }
            compute(buf);            // hides A-load latency
            if (more) packA2(buf ^ 1);   // waits vmcnt(4): A regs only
            __syncthreads();         // drains B + lgkm
            buf ^= 1;
        }
    }

    // ---- epilogue ----
    if (mode == 2 && p == 0 && fout) {
        // fused: out = acc + bias + old (f32, coalesced float4)
#pragma unroll
        for (int m = 0; m < 8; m++) {
            long node = rr0 + wr * 128 + m * 16 + lr;
#pragma unroll
            for (int n = 0; n < 4; n++) {
                int col = n0 + wc * 64 + n * 16 + hk * 4;
                float4 bb = *(const float4*)&bias[col];
                float4 ov = *(const float4*)&oldv[node * 1024 + col];
                float4 r;
                r.x = acc[m][n][0] + bb.x + ov.x;
                r.y = acc[m][n][1] + bb.y + ov.y;
                r.z = acc[m][n][2] + bb.z + ov.z;
                r.w = acc[m][n][3] + bb.w + ov.w;
                *(float4*)&fout[node * 1024 + col] = r;
            }
        }
        return;
    }
    const bool use_bias = bias && (mode == 0 || p == 0);
#pragma unroll
    for (int m = 0; m < 8; m++) {
        long rit = wr * 128 + m * 16 + lr;
        u16* crow = C + cbase + rit * (size_t)ldc;
#pragma unroll
        for (int n = 0; n < 4; n++) {
            int col = n0 + wc * 64 + n * 16 + hk * 4;
            float4 bb = use_bias ? *(const float4*)&bias[(size_t)zi * bsz + col]
                                 : (float4){0.f, 0.f, 0.f, 0.f};
            float v0 = acc[m][n][0] + bb.x;
            float v1 = acc[m][n][1] + bb.y;
            float v2 = acc[m][n][2] + bb.z;
            float v3 = acc[m][n][3] + bb.w;
            if (act) {
                v0 = v0 * (1.0f / (1.0f + __expf(-v0)));
                v1 = v1 * (1.0f / (1.0f + __expf(-v1)));
                v2 = v2 * (1.0f / (1.0f + __expf(-v2)));
                v3 = v3 * (1.0f / (1.0f + __expf(-v3)));
            }
            uint2 st;
            st.x = (unsigned)f2bf(v0) | ((unsigned)f2bf(v1) << 16);
            st.y = (unsigned)f2bf(v2) | ((unsigned)f2bf(v3) << 16);
            *(uint2*)(crow + col) = st;
        }
    }
}

// ---------------- tensor product + residual -> f0', tv planes (8 elems/thread) ----------------
__global__ void tp_res(const u16* __restrict__ xl, const u16* xr_,
                       const float* __restrict__ tpw, const u16* __restrict__ xv,
                       u16* f0, u16* tv, long ps)
{
    int t = blockIdx.x * 256 + threadIdx.x;
    long n = t >> 5;
    int u0 = (t & 31) * 8;
    size_t o = (size_t)n * 256 + u0;

    S8 S1, AX, AY, AZ, S2, BX, BY, BZ, XS, RX, RY, RZ;
    S1.v = *(const short8*)(xl + o);
    AX.v = *(const short8*)(xl + ps + o);
    AY.v = *(const short8*)(xl + 2 * ps + o);
    AZ.v = *(const short8*)(xl + 3 * ps + o);
    S2.v = *(const short8*)(xr_ + o);
    BX.v = *(const short8*)(xr_ + ps + o);
    BY.v = *(const short8*)(xr_ + 2 * ps + o);
    BZ.v = *(const short8*)(xr_ + 3 * ps + o);
    XS.v = *(const short8*)(f0 + (size_t)n * 512 + u0);
    RX.v = *(const short8*)(xv + o);
    RY.v = *(const short8*)(xv + ps + o);
    RZ.v = *(const short8*)(xv + 2 * ps + o);

    float W[5][8];
#pragma unroll
    for (int q = 0; q < 5; q++) {
        float4 a = *(const float4*)(tpw + q * 256 + u0);
        float4 b = *(const float4*)(tpw + q * 256 + u0 + 4);
        W[q][0] = a.x; W[q][1] = a.y; W[q][2] = a.z; W[q][3] = a.w;
        W[q][4] = b.x; W[q][5] = b.y; W[q][6] = b.z; W[q][7] = b.w;
    }

    S8 O0, NV, TX, TY, TZ;
#pragma unroll
    for (int j = 0; j < 8; j++) {
        float s1 = bf2f(S1.h[j]), a1x = bf2f(AX.h[j]), a1y = bf2f(AY.h[j]), a1z = bf2f(AZ.h[j]);
        float s2 = bf2f(S2.h[j]), b1x = bf2f(BX.h[j]), b1y = bf2f(BY.h[j]), b1z = bf2f(BZ.h[j]);
        float dot = a1x * b1x + a1y * b1y + a1z * b1z;
        float cx = a1y * b1z - a1z * b1y;
        float cy = a1z * b1x - a1x * b1z;
        float cz = a1x * b1y - a1y * b1x;
        float out0 = A0C * (W[0][j] * s1 * s2 + W[3][j] * INV3C * dot) + bf2f(XS.h[j]);
        float ox = A1C * (INV3C * (W[1][j] * s1 * b1x + W[2][j] * s2 * a1x) + INV6C * W[4][j] * cx) + bf2f(RX.h[j]);
        float oy = A1C * (INV3C * (W[1][j] * s1 * b1y + W[2][j] * s2 * a1y) + INV6C * W[4][j] * cy) + bf2f(RY.h[j]);
        float oz = A1C * (INV3C * (W[1][j] * s1 * b1z + W[2][j] * s2 * a1z) + INV6C * W[4][j] * cz) + bf2f(RZ.h[j]);
        float nv = sqrtf(ox * ox + oy * oy + oz * oz + 1e-12f);
        O0.h[j] = f2bf(out0);
        NV.h[j] = f2bf(nv);
        TX.h[j] = f2bf(ox); TY.h[j] = f2bf(oy); TZ.h[j] = f2bf(oz);
    }
    *(short8*)(f0 + (size_t)n * 512 + u0) = O0.v;
    *(short8*)(f0 + (size_t)n * 512 + 256 + u0) = NV.v;
    *(short8*)(tv + o) = TX.v;
    *(short8*)(tv + ps + o) = TY.v;
    *(short8*)(tv + 2 * ps + o) = TZ.v;
}

// ---------------- repack vector planes -> interleaved + old_fii ----------------
// (scalar plane now written directly by lin3's fused epilogue)
__global__ void repack(const u16* __restrict__ outp, const float* __restrict__ old,
                       float* __restrict__ out, long ps)
{
    int t = blockIdx.x * 256 + threadIdx.x;
    long n = t >> 5;
    int u0 = (t & 31) * 8;
    size_t o = (size_t)n * 256 + u0;

    S8 VX, VY, VZ;
    VX.v = *(const short8*)(outp + ps + o);
    VY.v = *(const short8*)(outp + 2 * ps + o);
    VZ.v = *(const short8*)(outp + 3 * ps + o);

    const float* oldr = old + (size_t)n * 1024;
    float* outr = out + (size_t)n * 1024;

    float vv[24];
#pragma unroll
    for (int j = 0; j < 8; j++) {
        vv[3 * j] = bf2f(VX.h[j]);
        vv[3 * j + 1] = bf2f(VY.h[j]);
        vv[3 * j + 2] = bf2f(VZ.h[j]);
    }
#pragma unroll
    for (int i = 0; i < 6; i++) {
        float4 ov = *(const float4*)(oldr + 256 + 3 * u0 + 4 * i);
        float4 r;
        r.x = ov.x + vv[4 * i];
        r.y = ov.y + vv[4 * i + 1];
        r.z = ov.z + vv[4 * i + 2];
        r.w = ov.w + vv[4 * i + 3];
        *(float4*)(outr + 256 + 3 * u0 + 4 * i) = r;
    }
}

// weight offsets (u16 elements)
enum {
    OFF_ng12w1 = 0,        // 1024x512
    OFF_ng1w2  = 524288,   // 2 x 512x512 (stride 262144)
    OFF_ngow1  = 1048576,
    OFF_ngow2  = 1310720,
    OFF_l12w0  = 1572864,  // 2 x 256x256 (stride 65536)
    OFF_l12w1  = 1703936,  // 2 x 256x256
    OFF_l3w0   = 1835008,
    OFF_l3w1   = 1900544
};
#define BIAS_BYTE_OFF 3932160
enum { BOFF_mlp1 = 0, BOFF_mlp2 = 1024, BOFF_ngo1 = 2048, BOFF_ngo2 = 2560,
       BOFF_l12 = 3072, BOFF_l3 = 3584 };

extern "C" void kernel_launch(void* const* d_in, const int* in_sizes, int n_in,
                              void* d_out, int out_size, void* d_ws, size_t ws_size,
                              hipStream_t stream) {
    const float* x      = (const float*)d_in[0];
    const float* oldf   = (const float*)d_in[1];
    const float* ng1_w1 = (const float*)d_in[2];
    const float* ng1_b1 = (const float*)d_in[3];
    const float* ng1_w2 = (const float*)d_in[4];
    const float* ng1_b2 = (const float*)d_in[5];
    const float* ng2_w1 = (const float*)d_in[6];
    const float* ng2_b1 = (const float*)d_in[7];
    const float* ng2_w2 = (const float*)d_in[8];
    const float* ng2_b2 = (const float*)d_in[9];
    const float* ngo_w1 = (const float*)d_in[10];
    const float* ngo_b1 = (const float*)d_in[11];
    const float* ngo_w2 = (const float*)d_in[12];
    const float* ngo_b2 = (const float*)d_in[13];
    const float* l1_w0  = (const float*)d_in[14];
    const float* l1_b0  = (const float*)d_in[15];
    const float* l1_w1  = (const float*)d_in[16];
    const float* l2_w0  = (const float*)d_in[17];
    const float* l2_b0  = (const float*)d_in[18];
    const float* l2_w1  = (const float*)d_in[19];
    const float* l3_w0  = (const float*)d_in[20];
    const float* l3_b0  = (const float*)d_in[21];
    const float* l3_w1  = (const float*)d_in[22];
    const float* tpw    = (const float*)d_in[23];

    u16* wts = (u16*)d_ws;
    char* wsb = (char*)d_ws;
    float* biasf = (float*)(wsb + BIAS_BYTE_OFF);

    WArgs wa;
    wa.w[0]  = { ng1_w1, wts + OFF_ng12w1,          512, 1.0f };
    wa.w[1]  = { ng2_w1, wts + OFF_ng12w1 + 262144, 512, 1.0f };
    wa.w[2]  = { ng1_w2, wts + OFF_ng1w2,           512, 1.0f };
    wa.w[3]  = { ng2_w2, wts + OFF_ng1w2 + 262144,  512, 1.0f };
    wa.w[4]  = { ngo_w1, wts + OFF_ngow1,           512, 1.0f };
    wa.w[5]  = { ngo_w2, wts + OFF_ngow2,           512, 1.0f };
    wa.w[6]  = { l1_w0, wts + OFF_l12w0,            256, 0.0625f };
    wa.w[7]  = { l2_w0, wts + OFF_l12w0 + 65536,    256, 0.0625f };
    wa.w[8]  = { l1_w1, wts + OFF_l12w1,            256, 0.0625f };
    wa.w[9]  = { l2_w1, wts + OFF_l12w1 + 65536,    256, 0.0625f };
    wa.w[10] = { l3_w0, wts + OFF_l3w0,             256, 0.0625f };
    wa.w[11] = { l3_w1, wts + OFF_l3w1,             256, 0.0625f };
    cvt_weights<<<dim3(16, 16, 12), dim3(32, 8), 0, stream>>>(wa);

    BArgs ba;
    ba.b[0] = { ng1_b1, biasf + BOFF_mlp1,       512 };
    ba.b[1] = { ng2_b1, biasf + BOFF_mlp1 + 512, 512 };
    ba.b[2] = { ng1_b2, biasf + BOFF_mlp2,       512 };
    ba.b[3] = { ng2_b2, biasf + BOFF_mlp2 + 512, 512 };
    ba.b[4] = { ngo_b1, biasf + BOFF_ngo1,       512 };
    ba.b[5] = { ngo_b2, biasf + BOFF_ngo2,       512 };
    ba.b[6] = { l1_b0, biasf + BOFF_l12,         256 };
    ba.b[7] = { l2_b0, biasf + BOFF_l12 + 256,   256 };
    ba.b[8] = { l3_b0, biasf + BOFF_l3,          256 };
    pack_bias<<<9, 256, 0, stream>>>(ba);

    long Nn = (long)in_sizes[0] / 1024;

    // chunking: ws fit only (peak = 4MiB + Nc*10752 bytes)
    int c = 1;
    while (c < 256 &&
           (unsigned long long)(4ULL << 20) + (unsigned long long)(Nn / c) * 10752ULL > (unsigned long long)ws_size)
        c <<= 1;
    long Nc = Nn / c;

    u16* F0 = (u16*)(wsb + (4 << 20));       // [Nc,512]
    u16* H  = F0 + (size_t)Nc * 512;         // [Nc,1024]
    u16* G  = H + (size_t)Nc * 1024;         // [Nc,1024]
    u16* XV = G + (size_t)Nc * 1024;         // [3][Nc,256]
    u16* XL = XV + (size_t)Nc * 768;         // [2 sides][4 planes][Nc,256]
    long ps = Nc * 256;
    u16* XR = XL + 4 * ps;
    u16* TV = XR + ps;                       // aliases XR vector planes
    u16* OUTP = XL;                          // aliases XL (dead after tp_res)

    dim3 blk(512);
    const size_t SMEM = 131072;
    int mt = (int)(Nc / 256);
    int eb = (int)(Nc / 8);

    for (int ch = 0; ch < c; ++ch) {
        const float* xk  = x + (size_t)ch * Nc * 1024;
        const float* ok  = oldf + (size_t)ch * Nc * 1024;
        float* outk = (float*)d_out + (size_t)ch * Nc * 1024;

        prep_f0<<<eb, 256, 0, stream>>>(xk, F0, XV, ps);

        // MLP1 fused (ng1|ng2): H[Nc,1024] = silu(F0 @ W^T + b)
        gemm256<<<dim3(mt * 4, 1), blk, SMEM, stream>>>(F0, 512, 0, nullptr, nullptr, 0, 0,
            wts + OFF_ng12w1, 0, 0, biasf + BOFF_mlp1, 0, H, 1024, 0, 0, 512, Nc, 0, 1, 2,
            nullptr, nullptr);
        // MLP2 z-batched: G[:, z*512:] = H[:, z*512:] @ w2_z^T + b
        gemm256<<<dim3(mt * 2, 2), blk, SMEM, stream>>>(H, 1024, 512, nullptr, nullptr, 0, 0,
            wts + OFF_ng1w2, 262144, 0, biasf + BOFF_mlp2, 512, G, 1024, 512, 0, 512, Nc, 0, 0, 1,
            nullptr, nullptr);
        // merged irrep-linears lin1/lin2: z=2 sides, M=4*Nc (plane 0 scalar, 1-3 gated XV)
        gemm256<<<dim3(mt * 4, 2), blk, SMEM, stream>>>(G, 1024, 512, XV, G, 1024, 512,
            wts + OFF_l12w0, 65536, 131072, biasf + BOFF_l12, 256, XL, 256, 4 * ps, ps, 256, Nc, 2, 0, 0,
            nullptr, nullptr);

        // tensor product + residual -> F0', TV
        tp_res<<<eb, 256, 0, stream>>>(XL, XR, tpw, XV, F0, TV, ps);

        // ngo MLP (N=512)
        gemm256<<<dim3(mt * 2, 1), blk, SMEM, stream>>>(F0, 512, 0, nullptr, nullptr, 0, 0,
            wts + OFF_ngow1, 0, 0, biasf + BOFF_ngo1, 0, H, 512, 0, 0, 512, Nc, 0, 1, 1,
            nullptr, nullptr);
        gemm256<<<dim3(mt * 2, 1), blk, SMEM, stream>>>(H, 512, 0, nullptr, nullptr, 0, 0,
            wts + OFF_ngow2, 0, 0, biasf + BOFF_ngo2, 0, G, 512, 0, 0, 512, Nc, 0, 0, 1,
            nullptr, nullptr);
        // merged lin3: z=1, M=4*Nc; p0 scalar writes f32 out directly (+bias +old)
        gemm256<<<dim3(mt * 4, 1), blk, SMEM, stream>>>(G, 512, 0, TV, G, 512, 0,
            wts + OFF_l3w0, 0, 65536, biasf + BOFF_l3, 0, OUTP, 256, 0, ps, 256, Nc, 2, 0, 0,
            ok, outk);

        // repack vector planes + old_fii -> out
        repack<<<eb, 256, 0, stream>>>(OUTP, ok, outk, ps);
    }
}

// Round 14
// 496.948 us; speedup vs baseline: 1.0766x; 1.0413x over previous
//
#include <hip/hip_runtime.h>
#include <stdint.h>
#include <math.h>

typedef unsigned short u16;
typedef __attribute__((ext_vector_type(8))) short short8;
typedef __attribute__((ext_vector_type(4))) float f32x4;

#define A0C 0.44721359549995793f
#define A1C 0.77459666924148340f
#define INV3C 0.57735026918962584f
#define INV6C 0.40824829046386302f

__device__ __forceinline__ float bf2f(u16 u) {
    unsigned v = ((unsigned)u) << 16; float f; __builtin_memcpy(&f, &v, 4); return f;
}
__device__ __forceinline__ u16 f2bf(float f) {
    unsigned u; __builtin_memcpy(&u, &f, 4);
    u += 0x7fffu + ((u >> 16) & 1u);
    return (u16)(u >> 16);
}

__device__ __forceinline__ void gload_lds16(const void* g, void* l) {
    __builtin_amdgcn_global_load_lds((const __attribute__((address_space(1))) unsigned*)g,
                                     (__attribute__((address_space(3))) unsigned*)l, 16, 0, 0);
}

union S8 { short8 v; u16 h[8]; };

// ---------------- weight transpose + bf16 convert ----------------
struct WDesc { const float* s; u16* d; int n; float sc; };
struct WArgs { WDesc w[12]; };

__global__ void cvt_weights(WArgs args) {
    WDesc wd = args.w[blockIdx.z];
    int n = wd.n;
    int x0 = blockIdx.x * 32, y0 = blockIdx.y * 32;
    if (x0 >= n || y0 >= n) return;
    __shared__ float tile[32][33];
    int tx = threadIdx.x, ty = threadIdx.y;
#pragma unroll
    for (int j = 0; j < 4; j++)
        tile[ty + 8 * j][tx] = wd.s[(size_t)(y0 + ty + 8 * j) * n + x0 + tx];
    __syncthreads();
#pragma unroll
    for (int j = 0; j < 4; j++)
        wd.d[(size_t)(x0 + ty + 8 * j) * n + y0 + tx] = f2bf(tile[tx][ty + 8 * j] * wd.sc);
}

// ---------------- bias pack ----------------
struct BDesc { const float* s; float* d; int n; };
struct BArgs { BDesc b[9]; };
__global__ void pack_bias(BArgs a) {
    BDesc b = a.b[blockIdx.x];
    for (int i = threadIdx.x; i < b.n; i += 256) b.d[i] = b.s[i];
}

// ---------------- prep: f0 = [s,|v|] bf16, XV planar bf16 (8 elems/thread) ----------------
__global__ void prep_f0(const float* __restrict__ x, u16* __restrict__ f0,
                        u16* __restrict__ xv, long ps) {
    int t = blockIdx.x * 256 + threadIdx.x;
    long n = t >> 5;
    int u0 = (t & 31) * 8;
    const float* xr = x + (size_t)n * 1024;
    float4 s0 = *(const float4*)(xr + u0);
    float4 s1 = *(const float4*)(xr + u0 + 4);
    float vv[24];
#pragma unroll
    for (int i = 0; i < 6; i++) {
        float4 w = *(const float4*)(xr + 256 + 3 * u0 + 4 * i);
        vv[4 * i] = w.x; vv[4 * i + 1] = w.y; vv[4 * i + 2] = w.z; vv[4 * i + 3] = w.w;
    }
    float sc[8] = { s0.x, s0.y, s0.z, s0.w, s1.x, s1.y, s1.z, s1.w };
    S8 fs, fn, px, py, pz;
#pragma unroll
    for (int j = 0; j < 8; j++) {
        float a = vv[3 * j], b = vv[3 * j + 1], c = vv[3 * j + 2];
        float nv = sqrtf(a * a + b * b + c * c + 1e-12f);
        fs.h[j] = f2bf(sc[j]);
        fn.h[j] = f2bf(nv);
        px.h[j] = f2bf(a); py.h[j] = f2bf(b); pz.h[j] = f2bf(c);
    }
    size_t o = (size_t)n * 256 + u0;
    *(short8*)(f0 + (size_t)n * 512 + u0) = fs.v;
    *(short8*)(f0 + (size_t)n * 512 + 256 + u0) = fn.v;
    *(short8*)(xv + o) = px.v;
    *(short8*)(xv + ps + o) = py.v;
    *(short8*)(xv + 2 * ps + o) = pz.v;
}

// ---------------- GEMM 256x256 tile, BK=64, dbuf LDS, T2 swizzle ----------------
// a_direct path (mode 0 / p==0): T4 counted-vmcnt pipeline.
// mode 2 p>0 (gated): REORDERED staging — A reg-loads issued BEFORE stageB's
// gload_lds, pack AFTER compute (pack's wait only covers the A regs; B loads
// stay in flight across compute). Measured: lin12 108.6 -> 102.1 us (r13).
// MFMA operands SWAPPED (mfma(b,a)): lane&15 -> M-row, hk*4+reg -> N-col.
__global__ __launch_bounds__(512, 2)
void gemm256(const u16* __restrict__ Ap, int lda, long az,
             const u16* __restrict__ xsrc,
             const u16* __restrict__ gp, int gld, long gz,
             const u16* __restrict__ Bt, long bz, long bw,
             const float* __restrict__ bias, int bsz,
             u16* __restrict__ C, int ldc, long czs, long czp,
             int K, long nc, int mode, int act, int nshift)
{
    extern __shared__ __align__(16) u16 sm[];
    u16* As = sm;
    u16* Bs = sm + 32768;

    const int tid = threadIdx.x;
    const int lane = tid & 63;
    const int wid = tid >> 6;
    const int wr = wid >> 2, wc = wid & 3;
    const int lr = lane & 15, hk = lane >> 4;

    int nwg = gridDim.x;
    int lid = blockIdx.x;
    int wg;
    if ((nwg & 7) == 0) { int q = nwg >> 3; wg = (lid & 7) * q + (lid >> 3); }
    else wg = lid;
    const long row0 = (long)(wg >> nshift) * 256;
    const int n0 = (wg & ((1 << nshift) - 1)) * 256;
    const int zi = blockIdx.y;

    long p = 0, rr0 = row0;
    if (mode == 2) { p = row0 / nc; rr0 = row0 - p * nc; }

    const u16* Bz = Bt + (size_t)zi * bz + ((mode == 2 && p > 0) ? bw : 0);
    const long cbase = (mode == 2) ? (zi * czs + p * czp + rr0 * ldc)
                                   : (zi * czs + row0 * ldc);

    f32x4 acc[8][4];
#pragma unroll
    for (int m = 0; m < 8; m++)
#pragma unroll
        for (int n = 0; n < 4; n++) acc[m][n] = (f32x4){0.f, 0.f, 0.f, 0.f};

    auto stageB = [&](int buf, int kt) {
#pragma unroll
        for (int it = 0; it < 4; ++it) {
            int idx = it * 512 + tid;
            int r = idx >> 3, s = idx & 7;
            const u16* g = Bz + (size_t)(n0 + r) * K + kt + ((s ^ (r & 7)) * 8);
            u16* l = Bs + buf * 16384 + (size_t)(it * 512 + (tid & 0x1C0)) * 8;
            gload_lds16(g, l);
        }
    };
    auto stageA0 = [&](int buf, int kt) {
#pragma unroll
        for (int it = 0; it < 4; ++it) {
            int idx = it * 512 + tid;
            int r = idx >> 3, s = idx & 7;
            const u16* g = Ap + (size_t)zi * az + (rr0 + r) * (size_t)lda + kt + ((s ^ (r & 7)) * 8);
            u16* l = As + buf * 16384 + (size_t)(it * 512 + (tid & 0x1C0)) * 8;
            gload_lds16(g, l);
        }
    };

    // mode-2 A staging split: reg loads (issue-early) / pack+ds_write (late)
    S8 rg[4], rt[4];
    auto loadA2 = [&](int kt) {
#pragma unroll
        for (int it = 0; it < 4; ++it) {
            int idx = it * 512 + tid;
            int r = idx >> 3, s = idx & 7;
            int u = kt + s * 8;
            rg[it].v = *(const short8*)(gp + (size_t)zi * gz + (rr0 + r) * (size_t)gld + 256 + u);
            rt[it].v = *(const short8*)(xsrc + (size_t)(row0 - nc + r) * 256 + u);
        }
    };
    auto packA2 = [&](int buf) {
#pragma unroll
        for (int it = 0; it < 4; ++it) {
            int idx = it * 512 + tid;
            int r = idx >> 3, s = idx & 7;
            S8 pk;
#pragma unroll
            for (int j = 0; j < 8; j++) pk.h[j] = f2bf(bf2f(rt[it].h[j]) * bf2f(rg[it].h[j]));
            *(short8*)&As[buf * 16384 + ((size_t)r * 8 + (s ^ (r & 7))) * 8] = pk.v;
        }
    };

    auto compute = [&](int buf) {
        const int ao = buf * 16384, bo = buf * 16384;
#pragma unroll
        for (int kk = 0; kk < 2; ++kk) {
            short8 b[4];
#pragma unroll
            for (int n = 0; n < 4; n++) {
                int cb = wc * 64 + n * 16 + lr;
                int sl = (kk * 4 + hk) ^ (cb & 7);
                b[n] = *(const short8*)&Bs[bo + (size_t)cb * 64 + sl * 8];
            }
#pragma unroll
            for (int m = 0; m < 8; m++) {
                int ra = wr * 128 + m * 16 + lr;
                int sl = (kk * 4 + hk) ^ (ra & 7);
                short8 a = *(const short8*)&As[ao + (size_t)ra * 64 + sl * 8];
#pragma unroll
                for (int n = 0; n < 4; n++)
                    acc[m][n] = __builtin_amdgcn_mfma_f32_16x16x32_bf16(b[n], a, acc[m][n], 0, 0, 0);
            }
        }
    };

    const bool a_direct = (mode == 0) || (p == 0);
    const int nt = K >> 6;
    int buf = 0;

    if (a_direct) {
        stageB(0, 0);
        stageA0(0, 0);
        for (int t = 0; t < nt; ++t) {
            if (t + 1 < nt) {
                int kt = (t + 1) << 6;
                stageB(buf ^ 1, kt);
                stageA0(buf ^ 1, kt);
                asm volatile("s_waitcnt vmcnt(8)" ::: "memory");
            } else {
                asm volatile("s_waitcnt vmcnt(0)" ::: "memory");
            }
            __builtin_amdgcn_s_barrier();
            __builtin_amdgcn_sched_barrier(0);
            compute(buf);
            __builtin_amdgcn_s_barrier();
            buf ^= 1;
        }
    } else {
        loadA2(0);
        stageB(0, 0);
        packA2(0);
        __syncthreads();
        for (int t = 0; t < nt; ++t) {
            const bool more = (t + 1 < nt);
            if (more) {
                int kt = (t + 1) << 6;
                loadA2(kt);          // A regs first (oldest in vmcnt FIFO)
                stageB(buf ^ 1, kt); // B gload_lds younger -> stays in flight
            }
            compute(buf);            // hides A-load latency
            if (more) packA2(buf ^ 1);   // waits A regs only
            __syncthreads();         // drains B + lgkm
            buf ^= 1;
        }
    }

    // ---- epilogue: lane holds 4 consecutive cols -> packed 8B stores ----
    const bool use_bias = bias && (mode == 0 || p == 0);
#pragma unroll
    for (int m = 0; m < 8; m++) {
        long rit = wr * 128 + m * 16 + lr;
        u16* crow = C + cbase + rit * (size_t)ldc;
#pragma unroll
        for (int n = 0; n < 4; n++) {
            int col = n0 + wc * 64 + n * 16 + hk * 4;
            float4 bb = use_bias ? *(const float4*)&bias[(size_t)zi * bsz + col]
                                 : (float4){0.f, 0.f, 0.f, 0.f};
            float v0 = acc[m][n][0] + bb.x;
            float v1 = acc[m][n][1] + bb.y;
            float v2 = acc[m][n][2] + bb.z;
            float v3 = acc[m][n][3] + bb.w;
            if (act) {
                v0 = v0 * (1.0f / (1.0f + __expf(-v0)));
                v1 = v1 * (1.0f / (1.0f + __expf(-v1)));
                v2 = v2 * (1.0f / (1.0f + __expf(-v2)));
                v3 = v3 * (1.0f / (1.0f + __expf(-v3)));
            }
            uint2 st;
            st.x = (unsigned)f2bf(v0) | ((unsigned)f2bf(v1) << 16);
            st.y = (unsigned)f2bf(v2) | ((unsigned)f2bf(v3) << 16);
            *(uint2*)(crow + col) = st;
        }
    }
}

// ---------------- tensor product + residual -> f0', tv planes (8 elems/thread) ----------------
__global__ void tp_res(const u16* __restrict__ xl, const u16* xr_,
                       const float* __restrict__ tpw, const u16* __restrict__ xv,
                       u16* f0, u16* tv, long ps)
{
    int t = blockIdx.x * 256 + threadIdx.x;
    long n = t >> 5;
    int u0 = (t & 31) * 8;
    size_t o = (size_t)n * 256 + u0;

    S8 S1, AX, AY, AZ, S2, BX, BY, BZ, XS, RX, RY, RZ;
    S1.v = *(const short8*)(xl + o);
    AX.v = *(const short8*)(xl + ps + o);
    AY.v = *(const short8*)(xl + 2 * ps + o);
    AZ.v = *(const short8*)(xl + 3 * ps + o);
    S2.v = *(const short8*)(xr_ + o);
    BX.v = *(const short8*)(xr_ + ps + o);
    BY.v = *(const short8*)(xr_ + 2 * ps + o);
    BZ.v = *(const short8*)(xr_ + 3 * ps + o);
    XS.v = *(const short8*)(f0 + (size_t)n * 512 + u0);
    RX.v = *(const short8*)(xv + o);
    RY.v = *(const short8*)(xv + ps + o);
    RZ.v = *(const short8*)(xv + 2 * ps + o);

    float W[5][8];
#pragma unroll
    for (int q = 0; q < 5; q++) {
        float4 a = *(const float4*)(tpw + q * 256 + u0);
        float4 b = *(const float4*)(tpw + q * 256 + u0 + 4);
        W[q][0] = a.x; W[q][1] = a.y; W[q][2] = a.z; W[q][3] = a.w;
        W[q][4] = b.x; W[q][5] = b.y; W[q][6] = b.z; W[q][7] = b.w;
    }

    S8 O0, NV, TX, TY, TZ;
#pragma unroll
    for (int j = 0; j < 8; j++) {
        float s1 = bf2f(S1.h[j]), a1x = bf2f(AX.h[j]), a1y = bf2f(AY.h[j]), a1z = bf2f(AZ.h[j]);
        float s2 = bf2f(S2.h[j]), b1x = bf2f(BX.h[j]), b1y = bf2f(BY.h[j]), b1z = bf2f(BZ.h[j]);
        float dot = a1x * b1x + a1y * b1y + a1z * b1z;
        float cx = a1y * b1z - a1z * b1y;
        float cy = a1z * b1x - a1x * b1z;
        float cz = a1x * b1y - a1y * b1x;
        float out0 = A0C * (W[0][j] * s1 * s2 + W[3][j] * INV3C * dot) + bf2f(XS.h[j]);
        float ox = A1C * (INV3C * (W[1][j] * s1 * b1x + W[2][j] * s2 * a1x) + INV6C * W[4][j] * cx) + bf2f(RX.h[j]);
        float oy = A1C * (INV3C * (W[1][j] * s1 * b1y + W[2][j] * s2 * a1y) + INV6C * W[4][j] * cy) + bf2f(RY.h[j]);
        float oz = A1C * (INV3C * (W[1][j] * s1 * b1z + W[2][j] * s2 * a1z) + INV6C * W[4][j] * cz) + bf2f(RZ.h[j]);
        float nv = sqrtf(ox * ox + oy * oy + oz * oz + 1e-12f);
        O0.h[j] = f2bf(out0);
        NV.h[j] = f2bf(nv);
        TX.h[j] = f2bf(ox); TY.h[j] = f2bf(oy); TZ.h[j] = f2bf(oz);
    }
    *(short8*)(f0 + (size_t)n * 512 + u0) = O0.v;
    *(short8*)(f0 + (size_t)n * 512 + 256 + u0) = NV.v;
    *(short8*)(tv + o) = TX.v;
    *(short8*)(tv + ps + o) = TY.v;
    *(short8*)(tv + 2 * ps + o) = TZ.v;
}

// ---------------- repack planar -> interleaved + old_fii (8 elems/thread) ----------------
__global__ void repack(const u16* __restrict__ outp, const float* __restrict__ old,
                       float* __restrict__ out, long ps)
{
    int t = blockIdx.x * 256 + threadIdx.x;
    long n = t >> 5;
    int u0 = (t & 31) * 8;
    size_t o = (size_t)n * 256 + u0;

    S8 S, VX, VY, VZ;
    S.v  = *(const short8*)(outp + o);
    VX.v = *(const short8*)(outp + ps + o);
    VY.v = *(const short8*)(outp + 2 * ps + o);
    VZ.v = *(const short8*)(outp + 3 * ps + o);

    const float* oldr = old + (size_t)n * 1024;
    float* outr = out + (size_t)n * 1024;

#pragma unroll
    for (int i = 0; i < 2; i++) {
        float4 ov = *(const float4*)(oldr + u0 + 4 * i);
        float4 r;
        r.x = ov.x + bf2f(S.h[4 * i]);
        r.y = ov.y + bf2f(S.h[4 * i + 1]);
        r.z = ov.z + bf2f(S.h[4 * i + 2]);
        r.w = ov.w + bf2f(S.h[4 * i + 3]);
        *(float4*)(outr + u0 + 4 * i) = r;
    }
    float vv[24];
#pragma unroll
    for (int j = 0; j < 8; j++) {
        vv[3 * j] = bf2f(VX.h[j]);
        vv[3 * j + 1] = bf2f(VY.h[j]);
        vv[3 * j + 2] = bf2f(VZ.h[j]);
    }
#pragma unroll
    for (int i = 0; i < 6; i++) {
        float4 ov = *(const float4*)(oldr + 256 + 3 * u0 + 4 * i);
        float4 r;
        r.x = ov.x + vv[4 * i];
        r.y = ov.y + vv[4 * i + 1];
        r.z = ov.z + vv[4 * i + 2];
        r.w = ov.w + vv[4 * i + 3];
        *(float4*)(outr + 256 + 3 * u0 + 4 * i) = r;
    }
}

// weight offsets (u16 elements)
enum {
    OFF_ng12w1 = 0,        // 1024x512
    OFF_ng1w2  = 524288,   // 2 x 512x512 (stride 262144)
    OFF_ngow1  = 1048576,
    OFF_ngow2  = 1310720,
    OFF_l12w0  = 1572864,  // 2 x 256x256 (stride 65536)
    OFF_l12w1  = 1703936,  // 2 x 256x256
    OFF_l3w0   = 1835008,
    OFF_l3w1   = 1900544
};
#define BIAS_BYTE_OFF 3932160
enum { BOFF_mlp1 = 0, BOFF_mlp2 = 1024, BOFF_ngo1 = 2048, BOFF_ngo2 = 2560,
       BOFF_l12 = 3072, BOFF_l3 = 3584 };

extern "C" void kernel_launch(void* const* d_in, const int* in_sizes, int n_in,
                              void* d_out, int out_size, void* d_ws, size_t ws_size,
                              hipStream_t stream) {
    const float* x      = (const float*)d_in[0];
    const float* oldf   = (const float*)d_in[1];
    const float* ng1_w1 = (const float*)d_in[2];
    const float* ng1_b1 = (const float*)d_in[3];
    const float* ng1_w2 = (const float*)d_in[4];
    const float* ng1_b2 = (const float*)d_in[5];
    const float* ng2_w1 = (const float*)d_in[6];
    const float* ng2_b1 = (const float*)d_in[7];
    const float* ng2_w2 = (const float*)d_in[8];
    const float* ng2_b2 = (const float*)d_in[9];
    const float* ngo_w1 = (const float*)d_in[10];
    const float* ngo_b1 = (const float*)d_in[11];
    const float* ngo_w2 = (const float*)d_in[12];
    const float* ngo_b2 = (const float*)d_in[13];
    const float* l1_w0  = (const float*)d_in[14];
    const float* l1_b0  = (const float*)d_in[15];
    const float* l1_w1  = (const float*)d_in[16];
    const float* l2_w0  = (const float*)d_in[17];
    const float* l2_b0  = (const float*)d_in[18];
    const float* l2_w1  = (const float*)d_in[19];
    const float* l3_w0  = (const float*)d_in[20];
    const float* l3_b0  = (const float*)d_in[21];
    const float* l3_w1  = (const float*)d_in[22];
    const float* tpw    = (const float*)d_in[23];

    u16* wts = (u16*)d_ws;
    char* wsb = (char*)d_ws;
    float* biasf = (float*)(wsb + BIAS_BYTE_OFF);

    WArgs wa;
    wa.w[0]  = { ng1_w1, wts + OFF_ng12w1,          512, 1.0f };
    wa.w[1]  = { ng2_w1, wts + OFF_ng12w1 + 262144, 512, 1.0f };
    wa.w[2]  = { ng1_w2, wts + OFF_ng1w2,           512, 1.0f };
    wa.w[3]  = { ng2_w2, wts + OFF_ng1w2 + 262144,  512, 1.0f };
    wa.w[4]  = { ngo_w1, wts + OFF_ngow1,           512, 1.0f };
    wa.w[5]  = { ngo_w2, wts + OFF_ngow2,           512, 1.0f };
    wa.w[6]  = { l1_w0, wts + OFF_l12w0,            256, 0.0625f };
    wa.w[7]  = { l2_w0, wts + OFF_l12w0 + 65536,    256, 0.0625f };
    wa.w[8]  = { l1_w1, wts + OFF_l12w1,            256, 0.0625f };
    wa.w[9]  = { l2_w1, wts + OFF_l12w1 + 65536,    256, 0.0625f };
    wa.w[10] = { l3_w0, wts + OFF_l3w0,             256, 0.0625f };
    wa.w[11] = { l3_w1, wts + OFF_l3w1,             256, 0.0625f };
    cvt_weights<<<dim3(16, 16, 12), dim3(32, 8), 0, stream>>>(wa);

    BArgs ba;
    ba.b[0] = { ng1_b1, biasf + BOFF_mlp1,       512 };
    ba.b[1] = { ng2_b1, biasf + BOFF_mlp1 + 512, 512 };
    ba.b[2] = { ng1_b2, biasf + BOFF_mlp2,       512 };
    ba.b[3] = { ng2_b2, biasf + BOFF_mlp2 + 512, 512 };
    ba.b[4] = { ngo_b1, biasf + BOFF_ngo1,       512 };
    ba.b[5] = { ngo_b2, biasf + BOFF_ngo2,       512 };
    ba.b[6] = { l1_b0, biasf + BOFF_l12,         256 };
    ba.b[7] = { l2_b0, biasf + BOFF_l12 + 256,   256 };
    ba.b[8] = { l3_b0, biasf + BOFF_l3,          256 };
    pack_bias<<<9, 256, 0, stream>>>(ba);

    long Nn = (long)in_sizes[0] / 1024;

    // chunking: ws fit only (peak = 4MiB + Nc*10752 bytes)
    int c = 1;
    while (c < 256 &&
           (unsigned long long)(4ULL << 20) + (unsigned long long)(Nn / c) * 10752ULL > (unsigned long long)ws_size)
        c <<= 1;
    long Nc = Nn / c;

    u16* F0 = (u16*)(wsb + (4 << 20));       // [Nc,512]
    u16* H  = F0 + (size_t)Nc * 512;         // [Nc,1024]
    u16* G  = H + (size_t)Nc * 1024;         // [Nc,1024]
    u16* XV = G + (size_t)Nc * 1024;         // [3][Nc,256]
    u16* XL = XV + (size_t)Nc * 768;         // [2 sides][4 planes][Nc,256]
    long ps = Nc * 256;
    u16* XR = XL + 4 * ps;
    u16* TV = XR + ps;                       // aliases XR vector planes
    u16* OUTP = XL;                          // aliases XL (dead after tp_res)

    dim3 blk(512);
    const size_t SMEM = 131072;
    int mt = (int)(Nc / 256);
    int eb = (int)(Nc / 8);

    for (int ch = 0; ch < c; ++ch) {
        const float* xk  = x + (size_t)ch * Nc * 1024;
        const float* ok  = oldf + (size_t)ch * Nc * 1024;
        float* outk = (float*)d_out + (size_t)ch * Nc * 1024;

        prep_f0<<<eb, 256, 0, stream>>>(xk, F0, XV, ps);

        // MLP1 fused (ng1|ng2): H[Nc,1024] = silu(F0 @ W^T + b)
        gemm256<<<dim3(mt * 4, 1), blk, SMEM, stream>>>(F0, 512, 0, nullptr, nullptr, 0, 0,
            wts + OFF_ng12w1, 0, 0, biasf + BOFF_mlp1, 0, H, 1024, 0, 0, 512, Nc, 0, 1, 2);
        // MLP2 z-batched: G[:, z*512:] = H[:, z*512:] @ w2_z^T + b
        gemm256<<<dim3(mt * 2, 2), blk, SMEM, stream>>>(H, 1024, 512, nullptr, nullptr, 0, 0,
            wts + OFF_ng1w2, 262144, 0, biasf + BOFF_mlp2, 512, G, 1024, 512, 0, 512, Nc, 0, 0, 1);
        // merged irrep-linears lin1/lin2: z=2 sides, M=4*Nc (plane 0 scalar, 1-3 gated XV)
        gemm256<<<dim3(mt * 4, 2), blk, SMEM, stream>>>(G, 1024, 512, XV, G, 1024, 512,
            wts + OFF_l12w0, 65536, 131072, biasf + BOFF_l12, 256, XL, 256, 4 * ps, ps, 256, Nc, 2, 0, 0);

        // tensor product + residual -> F0', TV
        tp_res<<<eb, 256, 0, stream>>>(XL, XR, tpw, XV, F0, TV, ps);

        // ngo MLP (N=512)
        gemm256<<<dim3(mt * 2, 1), blk, SMEM, stream>>>(F0, 512, 0, nullptr, nullptr, 0, 0,
            wts + OFF_ngow1, 0, 0, biasf + BOFF_ngo1, 0, H, 512, 0, 0, 512, Nc, 0, 1, 1);
        gemm256<<<dim3(mt * 2, 1), blk, SMEM, stream>>>(H, 512, 0, nullptr, nullptr, 0, 0,
            wts + OFF_ngow2, 0, 0, biasf + BOFF_ngo2, 0, G, 512, 0, 0, 512, Nc, 0, 0, 1);
        // merged lin3: z=1, M=4*Nc (plane 0 scalar from G, 1-3 gated TV)
        gemm256<<<dim3(mt * 4, 1), blk, SMEM, stream>>>(G, 512, 0, TV, G, 512, 0,
            wts + OFF_l3w0, 0, 65536, biasf + BOFF_l3, 0, OUTP, 256, 0, ps, 256, Nc, 2, 0, 0);

        // repack + old_fii -> out
        repack<<<eb, 256, 0, stream>>>(OUTP, ok, outk, ps);
    }
}

// Round 15
// 496.502 us; speedup vs baseline: 1.0776x; 1.0009x over previous
//
#include <hip/hip_runtime.h>
#include <stdint.h>
#include <math.h>

typedef unsigned short u16;
typedef __attribute__((ext_vector_type(8))) short short8;
typedef __attribute__((ext_vector_type(4))) float f32x4;

#define A0C 0.44721359549995793f
#define A1C 0.77459666924148340f
#define INV3C 0.57735026918962584f
#define INV6C 0.40824829046386302f

__device__ __forceinline__ float bf2f(u16 u) {
    unsigned v = ((unsigned)u) << 16; float f; __builtin_memcpy(&f, &v, 4); return f;
}
__device__ __forceinline__ u16 f2bf(float f) {
    unsigned u; __builtin_memcpy(&u, &f, 4);
    u += 0x7fffu + ((u >> 16) & 1u);
    return (u16)(u >> 16);
}

__device__ __forceinline__ void gload_lds16(const void* g, void* l) {
    __builtin_amdgcn_global_load_lds((const __attribute__((address_space(1))) unsigned*)g,
                                     (__attribute__((address_space(3))) unsigned*)l, 16, 0, 0);
}

union S8 { short8 v; u16 h[8]; };

// ---------------- weight transpose + bf16 convert ----------------
struct WDesc { const float* s; u16* d; int n; float sc; };
struct WArgs { WDesc w[12]; };

__global__ void cvt_weights(WArgs args) {
    WDesc wd = args.w[blockIdx.z];
    int n = wd.n;
    int x0 = blockIdx.x * 32, y0 = blockIdx.y * 32;
    if (x0 >= n || y0 >= n) return;
    __shared__ float tile[32][33];
    int tx = threadIdx.x, ty = threadIdx.y;
#pragma unroll
    for (int j = 0; j < 4; j++)
        tile[ty + 8 * j][tx] = wd.s[(size_t)(y0 + ty + 8 * j) * n + x0 + tx];
    __syncthreads();
#pragma unroll
    for (int j = 0; j < 4; j++)
        wd.d[(size_t)(x0 + ty + 8 * j) * n + y0 + tx] = f2bf(tile[tx][ty + 8 * j] * wd.sc);
}

// ---------------- bias pack ----------------
struct BDesc { const float* s; float* d; int n; };
struct BArgs { BDesc b[9]; };
__global__ void pack_bias(BArgs a) {
    BDesc b = a.b[blockIdx.x];
    for (int i = threadIdx.x; i < b.n; i += 256) b.d[i] = b.s[i];
}

// ---------------- prep: f0 = [s,|v|] bf16, XV planar bf16 (8 elems/thread) ----------------
__global__ void prep_f0(const float* __restrict__ x, u16* __restrict__ f0,
                        u16* __restrict__ xv, long ps) {
    int t = blockIdx.x * 256 + threadIdx.x;
    long n = t >> 5;
    int u0 = (t & 31) * 8;
    const float* xr = x + (size_t)n * 1024;
    float4 s0 = *(const float4*)(xr + u0);
    float4 s1 = *(const float4*)(xr + u0 + 4);
    float vv[24];
#pragma unroll
    for (int i = 0; i < 6; i++) {
        float4 w = *(const float4*)(xr + 256 + 3 * u0 + 4 * i);
        vv[4 * i] = w.x; vv[4 * i + 1] = w.y; vv[4 * i + 2] = w.z; vv[4 * i + 3] = w.w;
    }
    float sc[8] = { s0.x, s0.y, s0.z, s0.w, s1.x, s1.y, s1.z, s1.w };
    S8 fs, fn, px, py, pz;
#pragma unroll
    for (int j = 0; j < 8; j++) {
        float a = vv[3 * j], b = vv[3 * j + 1], c = vv[3 * j + 2];
        float nv = sqrtf(a * a + b * b + c * c + 1e-12f);
        fs.h[j] = f2bf(sc[j]);
        fn.h[j] = f2bf(nv);
        px.h[j] = f2bf(a); py.h[j] = f2bf(b); pz.h[j] = f2bf(c);
    }
    size_t o = (size_t)n * 256 + u0;
    *(short8*)(f0 + (size_t)n * 512 + u0) = fs.v;
    *(short8*)(f0 + (size_t)n * 512 + 256 + u0) = fn.v;
    *(short8*)(xv + o) = px.v;
    *(short8*)(xv + ps + o) = py.v;
    *(short8*)(xv + 2 * ps + o) = pz.v;
}

// ---------------- GEMM 256x256 tile, BK=64, dbuf LDS, T2 swizzle ----------------
// a_direct path (mode 0 / p==0): T4 counted-vmcnt pipeline.
// mode 2 p>0 (gated): reordered staging (A regs before stageB; pack after
// compute) — measured win r13 (lin12 108.6 -> 102.1 us).
// T5: s_setprio(1) around the MFMA cluster (phase-split loop -> scheduler can
// favor MFMA-entering waves over load-issuing waves).
// MFMA operands SWAPPED (mfma(b,a)): lane&15 -> M-row, hk*4+reg -> N-col.
__global__ __launch_bounds__(512, 2)
void gemm256(const u16* __restrict__ Ap, int lda, long az,
             const u16* __restrict__ xsrc,
             const u16* __restrict__ gp, int gld, long gz,
             const u16* __restrict__ Bt, long bz, long bw,
             const float* __restrict__ bias, int bsz,
             u16* __restrict__ C, int ldc, long czs, long czp,
             int K, long nc, int mode, int act, int nshift)
{
    extern __shared__ __align__(16) u16 sm[];
    u16* As = sm;
    u16* Bs = sm + 32768;

    const int tid = threadIdx.x;
    const int lane = tid & 63;
    const int wid = tid >> 6;
    const int wr = wid >> 2, wc = wid & 3;
    const int lr = lane & 15, hk = lane >> 4;

    int nwg = gridDim.x;
    int lid = blockIdx.x;
    int wg;
    if ((nwg & 7) == 0) { int q = nwg >> 3; wg = (lid & 7) * q + (lid >> 3); }
    else wg = lid;
    const long row0 = (long)(wg >> nshift) * 256;
    const int n0 = (wg & ((1 << nshift) - 1)) * 256;
    const int zi = blockIdx.y;

    long p = 0, rr0 = row0;
    if (mode == 2) { p = row0 / nc; rr0 = row0 - p * nc; }

    const u16* Bz = Bt + (size_t)zi * bz + ((mode == 2 && p > 0) ? bw : 0);
    const long cbase = (mode == 2) ? (zi * czs + p * czp + rr0 * ldc)
                                   : (zi * czs + row0 * ldc);

    f32x4 acc[8][4];
#pragma unroll
    for (int m = 0; m < 8; m++)
#pragma unroll
        for (int n = 0; n < 4; n++) acc[m][n] = (f32x4){0.f, 0.f, 0.f, 0.f};

    auto stageB = [&](int buf, int kt) {
#pragma unroll
        for (int it = 0; it < 4; ++it) {
            int idx = it * 512 + tid;
            int r = idx >> 3, s = idx & 7;
            const u16* g = Bz + (size_t)(n0 + r) * K + kt + ((s ^ (r & 7)) * 8);
            u16* l = Bs + buf * 16384 + (size_t)(it * 512 + (tid & 0x1C0)) * 8;
            gload_lds16(g, l);
        }
    };
    auto stageA0 = [&](int buf, int kt) {
#pragma unroll
        for (int it = 0; it < 4; ++it) {
            int idx = it * 512 + tid;
            int r = idx >> 3, s = idx & 7;
            const u16* g = Ap + (size_t)zi * az + (rr0 + r) * (size_t)lda + kt + ((s ^ (r & 7)) * 8);
            u16* l = As + buf * 16384 + (size_t)(it * 512 + (tid & 0x1C0)) * 8;
            gload_lds16(g, l);
        }
    };

    // mode-2 A staging split: reg loads (issue-early) / pack+ds_write (late)
    S8 rg[4], rt[4];
    auto loadA2 = [&](int kt) {
#pragma unroll
        for (int it = 0; it < 4; ++it) {
            int idx = it * 512 + tid;
            int r = idx >> 3, s = idx & 7;
            int u = kt + s * 8;
            rg[it].v = *(const short8*)(gp + (size_t)zi * gz + (rr0 + r) * (size_t)gld + 256 + u);
            rt[it].v = *(const short8*)(xsrc + (size_t)(row0 - nc + r) * 256 + u);
        }
    };
    auto packA2 = [&](int buf) {
#pragma unroll
        for (int it = 0; it < 4; ++it) {
            int idx = it * 512 + tid;
            int r = idx >> 3, s = idx & 7;
            S8 pk;
#pragma unroll
            for (int j = 0; j < 8; j++) pk.h[j] = f2bf(bf2f(rt[it].h[j]) * bf2f(rg[it].h[j]));
            *(short8*)&As[buf * 16384 + ((size_t)r * 8 + (s ^ (r & 7))) * 8] = pk.v;
        }
    };

    auto compute = [&](int buf) {
        const int ao = buf * 16384, bo = buf * 16384;
        __builtin_amdgcn_s_setprio(1);
#pragma unroll
        for (int kk = 0; kk < 2; ++kk) {
            short8 b[4];
#pragma unroll
            for (int n = 0; n < 4; n++) {
                int cb = wc * 64 + n * 16 + lr;
                int sl = (kk * 4 + hk) ^ (cb & 7);
                b[n] = *(const short8*)&Bs[bo + (size_t)cb * 64 + sl * 8];
            }
#pragma unroll
            for (int m = 0; m < 8; m++) {
                int ra = wr * 128 + m * 16 + lr;
                int sl = (kk * 4 + hk) ^ (ra & 7);
                short8 a = *(const short8*)&As[ao + (size_t)ra * 64 + sl * 8];
#pragma unroll
                for (int n = 0; n < 4; n++)
                    acc[m][n] = __builtin_amdgcn_mfma_f32_16x16x32_bf16(b[n], a, acc[m][n], 0, 0, 0);
            }
        }
        __builtin_amdgcn_s_setprio(0);
    };

    const bool a_direct = (mode == 0) || (p == 0);
    const int nt = K >> 6;
    int buf = 0;

    if (a_direct) {
        stageB(0, 0);
        stageA0(0, 0);
        for (int t = 0; t < nt; ++t) {
            if (t + 1 < nt) {
                int kt = (t + 1) << 6;
                stageB(buf ^ 1, kt);
                stageA0(buf ^ 1, kt);
                asm volatile("s_waitcnt vmcnt(8)" ::: "memory");
            } else {
                asm volatile("s_waitcnt vmcnt(0)" ::: "memory");
            }
            __builtin_amdgcn_s_barrier();
            __builtin_amdgcn_sched_barrier(0);
            compute(buf);
            __builtin_amdgcn_s_barrier();
            buf ^= 1;
        }
    } else {
        loadA2(0);
        stageB(0, 0);
        packA2(0);
        __syncthreads();
        for (int t = 0; t < nt; ++t) {
            const bool more = (t + 1 < nt);
            if (more) {
                int kt = (t + 1) << 6;
                loadA2(kt);          // A regs first (oldest in vmcnt FIFO)
                stageB(buf ^ 1, kt); // B gload_lds younger -> stays in flight
            }
            compute(buf);            // hides A-load latency
            if (more) packA2(buf ^ 1);   // waits A regs only
            __syncthreads();         // drains B + lgkm
            buf ^= 1;
        }
    }

    // ---- epilogue: lane holds 4 consecutive cols -> packed 8B stores ----
    const bool use_bias = bias && (mode == 0 || p == 0);
#pragma unroll
    for (int m = 0; m < 8; m++) {
        long rit = wr * 128 + m * 16 + lr;
        u16* crow = C + cbase + rit * (size_t)ldc;
#pragma unroll
        for (int n = 0; n < 4; n++) {
            int col = n0 + wc * 64 + n * 16 + hk * 4;
            float4 bb = use_bias ? *(const float4*)&bias[(size_t)zi * bsz + col]
                                 : (float4){0.f, 0.f, 0.f, 0.f};
            float v0 = acc[m][n][0] + bb.x;
            float v1 = acc[m][n][1] + bb.y;
            float v2 = acc[m][n][2] + bb.z;
            float v3 = acc[m][n][3] + bb.w;
            if (act) {
                v0 = v0 * (1.0f / (1.0f + __expf(-v0)));
                v1 = v1 * (1.0f / (1.0f + __expf(-v1)));
                v2 = v2 * (1.0f / (1.0f + __expf(-v2)));
                v3 = v3 * (1.0f / (1.0f + __expf(-v3)));
            }
            uint2 st;
            st.x = (unsigned)f2bf(v0) | ((unsigned)f2bf(v1) << 16);
            st.y = (unsigned)f2bf(v2) | ((unsigned)f2bf(v3) << 16);
            *(uint2*)(crow + col) = st;
        }
    }
}

// ---------------- tensor product + residual -> f0', tv planes (8 elems/thread) ----------------
__global__ void tp_res(const u16* __restrict__ xl, const u16* xr_,
                       const float* __restrict__ tpw, const u16* __restrict__ xv,
                       u16* f0, u16* tv, long ps)
{
    int t = blockIdx.x * 256 + threadIdx.x;
    long n = t >> 5;
    int u0 = (t & 31) * 8;
    size_t o = (size_t)n * 256 + u0;

    S8 S1, AX, AY, AZ, S2, BX, BY, BZ, XS, RX, RY, RZ;
    S1.v = *(const short8*)(xl + o);
    AX.v = *(const short8*)(xl + ps + o);
    AY.v = *(const short8*)(xl + 2 * ps + o);
    AZ.v = *(const short8*)(xl + 3 * ps + o);
    S2.v = *(const short8*)(xr_ + o);
    BX.v = *(const short8*)(xr_ + ps + o);
    BY.v = *(const short8*)(xr_ + 2 * ps + o);
    BZ.v = *(const short8*)(xr_ + 3 * ps + o);
    XS.v = *(const short8*)(f0 + (size_t)n * 512 + u0);
    RX.v = *(const short8*)(xv + o);
    RY.v = *(const short8*)(xv + ps + o);
    RZ.v = *(const short8*)(xv + 2 * ps + o);

    float W[5][8];
#pragma unroll
    for (int q = 0; q < 5; q++) {
        float4 a = *(const float4*)(tpw + q * 256 + u0);
        float4 b = *(const float4*)(tpw + q * 256 + u0 + 4);
        W[q][0] = a.x; W[q][1] = a.y; W[q][2] = a.z; W[q][3] = a.w;
        W[q][4] = b.x; W[q][5] = b.y; W[q][6] = b.z; W[q][7] = b.w;
    }

    S8 O0, NV, TX, TY, TZ;
#pragma unroll
    for (int j = 0; j < 8; j++) {
        float s1 = bf2f(S1.h[j]), a1x = bf2f(AX.h[j]), a1y = bf2f(AY.h[j]), a1z = bf2f(AZ.h[j]);
        float s2 = bf2f(S2.h[j]), b1x = bf2f(BX.h[j]), b1y = bf2f(BY.h[j]), b1z = bf2f(BZ.h[j]);
        float dot = a1x * b1x + a1y * b1y + a1z * b1z;
        float cx = a1y * b1z - a1z * b1y;
        float cy = a1z * b1x - a1x * b1z;
        float cz = a1x * b1y - a1y * b1x;
        float out0 = A0C * (W[0][j] * s1 * s2 + W[3][j] * INV3C * dot) + bf2f(XS.h[j]);
        float ox = A1C * (INV3C * (W[1][j] * s1 * b1x + W[2][j] * s2 * a1x) + INV6C * W[4][j] * cx) + bf2f(RX.h[j]);
        float oy = A1C * (INV3C * (W[1][j] * s1 * b1y + W[2][j] * s2 * a1y) + INV6C * W[4][j] * cy) + bf2f(RY.h[j]);
        float oz = A1C * (INV3C * (W[1][j] * s1 * b1z + W[2][j] * s2 * a1z) + INV6C * W[4][j] * cz) + bf2f(RZ.h[j]);
        float nv = sqrtf(ox * ox + oy * oy + oz * oz + 1e-12f);
        O0.h[j] = f2bf(out0);
        NV.h[j] = f2bf(nv);
        TX.h[j] = f2bf(ox); TY.h[j] = f2bf(oy); TZ.h[j] = f2bf(oz);
    }
    *(short8*)(f0 + (size_t)n * 512 + u0) = O0.v;
    *(short8*)(f0 + (size_t)n * 512 + 256 + u0) = NV.v;
    *(short8*)(tv + o) = TX.v;
    *(short8*)(tv + ps + o) = TY.v;
    *(short8*)(tv + 2 * ps + o) = TZ.v;
}

// ---------------- repack planar -> interleaved + old_fii (8 elems/thread) ----------------
__global__ void repack(const u16* __restrict__ outp, const float* __restrict__ old,
                       float* __restrict__ out, long ps)
{
    int t = blockIdx.x * 256 + threadIdx.x;
    long n = t >> 5;
    int u0 = (t & 31) * 8;
    size_t o = (size_t)n * 256 + u0;

    S8 S, VX, VY, VZ;
    S.v  = *(const short8*)(outp + o);
    VX.v = *(const short8*)(outp + ps + o);
    VY.v = *(const short8*)(outp + 2 * ps + o);
    VZ.v = *(const short8*)(outp + 3 * ps + o);

    const float* oldr = old + (size_t)n * 1024;
    float* outr = out + (size_t)n * 1024;

#pragma unroll
    for (int i = 0; i < 2; i++) {
        float4 ov = *(const float4*)(oldr + u0 + 4 * i);
        float4 r;
        r.x = ov.x + bf2f(S.h[4 * i]);
        r.y = ov.y + bf2f(S.h[4 * i + 1]);
        r.z = ov.z + bf2f(S.h[4 * i + 2]);
        r.w = ov.w + bf2f(S.h[4 * i + 3]);
        *(float4*)(outr + u0 + 4 * i) = r;
    }
    float vv[24];
#pragma unroll
    for (int j = 0; j < 8; j++) {
        vv[3 * j] = bf2f(VX.h[j]);
        vv[3 * j + 1] = bf2f(VY.h[j]);
        vv[3 * j + 2] = bf2f(VZ.h[j]);
    }
#pragma unroll
    for (int i = 0; i < 6; i++) {
        float4 ov = *(const float4*)(oldr + 256 + 3 * u0 + 4 * i);
        float4 r;
        r.x = ov.x + vv[4 * i];
        r.y = ov.y + vv[4 * i + 1];
        r.z = ov.z + vv[4 * i + 2];
        r.w = ov.w + vv[4 * i + 3];
        *(float4*)(outr + 256 + 3 * u0 + 4 * i) = r;
    }
}

// weight offsets (u16 elements)
enum {
    OFF_ng12w1 = 0,        // 1024x512
    OFF_ng1w2  = 524288,   // 2 x 512x512 (stride 262144)
    OFF_ngow1  = 1048576,
    OFF_ngow2  = 1310720,
    OFF_l12w0  = 1572864,  // 2 x 256x256 (stride 65536)
    OFF_l12w1  = 1703936,  // 2 x 256x256
    OFF_l3w0   = 1835008,
    OFF_l3w1   = 1900544
};
#define BIAS_BYTE_OFF 3932160
enum { BOFF_mlp1 = 0, BOFF_mlp2 = 1024, BOFF_ngo1 = 2048, BOFF_ngo2 = 2560,
       BOFF_l12 = 3072, BOFF_l3 = 3584 };

extern "C" void kernel_launch(void* const* d_in, const int* in_sizes, int n_in,
                              void* d_out, int out_size, void* d_ws, size_t ws_size,
                              hipStream_t stream) {
    const float* x      = (const float*)d_in[0];
    const float* oldf   = (const float*)d_in[1];
    const float* ng1_w1 = (const float*)d_in[2];
    const float* ng1_b1 = (const float*)d_in[3];
    const float* ng1_w2 = (const float*)d_in[4];
    const float* ng1_b2 = (const float*)d_in[5];
    const float* ng2_w1 = (const float*)d_in[6];
    const float* ng2_b1 = (const float*)d_in[7];
    const float* ng2_w2 = (const float*)d_in[8];
    const float* ng2_b2 = (const float*)d_in[9];
    const float* ngo_w1 = (const float*)d_in[10];
    const float* ngo_b1 = (const float*)d_in[11];
    const float* ngo_w2 = (const float*)d_in[12];
    const float* ngo_b2 = (const float*)d_in[13];
    const float* l1_w0  = (const float*)d_in[14];
    const float* l1_b0  = (const float*)d_in[15];
    const float* l1_w1  = (const float*)d_in[16];
    const float* l2_w0  = (const float*)d_in[17];
    const float* l2_b0  = (const float*)d_in[18];
    const float* l2_w1  = (const float*)d_in[19];
    const float* l3_w0  = (const float*)d_in[20];
    const float* l3_b0  = (const float*)d_in[21];
    const float* l3_w1  = (const float*)d_in[22];
    const float* tpw    = (const float*)d_in[23];

    u16* wts = (u16*)d_ws;
    char* wsb = (char*)d_ws;
    float* biasf = (float*)(wsb + BIAS_BYTE_OFF);

    WArgs wa;
    wa.w[0]  = { ng1_w1, wts + OFF_ng12w1,          512, 1.0f };
    wa.w[1]  = { ng2_w1, wts + OFF_ng12w1 + 262144, 512, 1.0f };
    wa.w[2]  = { ng1_w2, wts + OFF_ng1w2,           512, 1.0f };
    wa.w[3]  = { ng2_w2, wts + OFF_ng1w2 + 262144,  512, 1.0f };
    wa.w[4]  = { ngo_w1, wts + OFF_ngow1,           512, 1.0f };
    wa.w[5]  = { ngo_w2, wts + OFF_ngow2,           512, 1.0f };
    wa.w[6]  = { l1_w0, wts + OFF_l12w0,            256, 0.0625f };
    wa.w[7]  = { l2_w0, wts + OFF_l12w0 + 65536,    256, 0.0625f };
    wa.w[8]  = { l1_w1, wts + OFF_l12w1,            256, 0.0625f };
    wa.w[9]  = { l2_w1, wts + OFF_l12w1 + 65536,    256, 0.0625f };
    wa.w[10] = { l3_w0, wts + OFF_l3w0,             256, 0.0625f };
    wa.w[11] = { l3_w1, wts + OFF_l3w1,             256, 0.0625f };
    cvt_weights<<<dim3(16, 16, 12), dim3(32, 8), 0, stream>>>(wa);

    BArgs ba;
    ba.b[0] = { ng1_b1, biasf + BOFF_mlp1,       512 };
    ba.b[1] = { ng2_b1, biasf + BOFF_mlp1 + 512, 512 };
    ba.b[2] = { ng1_b2, biasf + BOFF_mlp2,       512 };
    ba.b[3] = { ng2_b2, biasf + BOFF_mlp2 + 512, 512 };
    ba.b[4] = { ngo_b1, biasf + BOFF_ngo1,       512 };
    ba.b[5] = { ngo_b2, biasf + BOFF_ngo2,       512 };
    ba.b[6] = { l1_b0, biasf + BOFF_l12,         256 };
    ba.b[7] = { l2_b0, biasf + BOFF_l12 + 256,   256 };
    ba.b[8] = { l3_b0, biasf + BOFF_l3,          256 };
    pack_bias<<<9, 256, 0, stream>>>(ba);

    long Nn = (long)in_sizes[0] / 1024;

    // chunking: ws fit only (peak = 4MiB + Nc*10752 bytes)
    int c = 1;
    while (c < 256 &&
           (unsigned long long)(4ULL << 20) + (unsigned long long)(Nn / c) * 10752ULL > (unsigned long long)ws_size)
        c <<= 1;
    long Nc = Nn / c;

    u16* F0 = (u16*)(wsb + (4 << 20));       // [Nc,512]
    u16* H  = F0 + (size_t)Nc * 512;         // [Nc,1024]
    u16* G  = H + (size_t)Nc * 1024;         // [Nc,1024]
    u16* XV = G + (size_t)Nc * 1024;         // [3][Nc,256]
    u16* XL = XV + (size_t)Nc * 768;         // [2 sides][4 planes][Nc,256]
    long ps = Nc * 256;
    u16* XR = XL + 4 * ps;
    u16* TV = XR + ps;                       // aliases XR vector planes
    u16* OUTP = XL;                          // aliases XL (dead after tp_res)

    dim3 blk(512);
    const size_t SMEM = 131072;
    int mt = (int)(Nc / 256);
    int eb = (int)(Nc / 8);

    for (int ch = 0; ch < c; ++ch) {
        const float* xk  = x + (size_t)ch * Nc * 1024;
        const float* ok  = oldf + (size_t)ch * Nc * 1024;
        float* outk = (float*)d_out + (size_t)ch * Nc * 1024;

        prep_f0<<<eb, 256, 0, stream>>>(xk, F0, XV, ps);

        // MLP1 fused (ng1|ng2): H[Nc,1024] = silu(F0 @ W^T + b)
        gemm256<<<dim3(mt * 4, 1), blk, SMEM, stream>>>(F0, 512, 0, nullptr, nullptr, 0, 0,
            wts + OFF_ng12w1, 0, 0, biasf + BOFF_mlp1, 0, H, 1024, 0, 0, 512, Nc, 0, 1, 2);
        // MLP2 z-batched: G[:, z*512:] = H[:, z*512:] @ w2_z^T + b
        gemm256<<<dim3(mt * 2, 2), blk, SMEM, stream>>>(H, 1024, 512, nullptr, nullptr, 0, 0,
            wts + OFF_ng1w2, 262144, 0, biasf + BOFF_mlp2, 512, G, 1024, 512, 0, 512, Nc, 0, 0, 1);
        // merged irrep-linears lin1/lin2: z=2 sides, M=4*Nc (plane 0 scalar, 1-3 gated XV)
        gemm256<<<dim3(mt * 4, 2), blk, SMEM, stream>>>(G, 1024, 512, XV, G, 1024, 512,
            wts + OFF_l12w0, 65536, 131072, biasf + BOFF_l12, 256, XL, 256, 4 * ps, ps, 256, Nc, 2, 0, 0);

        // tensor product + residual -> F0', TV
        tp_res<<<eb, 256, 0, stream>>>(XL, XR, tpw, XV, F0, TV, ps);

        // ngo MLP (N=512)
        gemm256<<<dim3(mt * 2, 1), blk, SMEM, stream>>>(F0, 512, 0, nullptr, nullptr, 0, 0,
            wts + OFF_ngow1, 0, 0, biasf + BOFF_ngo1, 0, H, 512, 0, 0, 512, Nc, 0, 1, 1);
        gemm256<<<dim3(mt * 2, 1), blk, SMEM, stream>>>(H, 512, 0, nullptr, nullptr, 0, 0,
            wts + OFF_ngow2, 0, 0, biasf + BOFF_ngo2, 0, G, 512, 0, 0, 512, Nc, 0, 0, 1);
        // merged lin3: z=1, M=4*Nc (plane 0 scalar from G, 1-3 gated TV)
        gemm256<<<dim3(mt * 4, 1), blk, SMEM, stream>>>(G, 512, 0, TV, G, 512, 0,
            wts + OFF_l3w0, 0, 65536, biasf + BOFF_l3, 0, OUTP, 256, 0, ps, 256, Nc, 2, 0, 0);

        // repack + old_fii -> out
        repack<<<eb, 256, 0, stream>>>(OUTP, ok, outk, ps);
    }
}